// Round 1
// baseline (5590.028 us; speedup 1.0000x reference)
//
#include <hip/hip_runtime.h>
#include <hip/hip_bf16.h>

// ResidualGNN: 2x GCNConv(128->128, relu) + FC(128->3, tanh) on N=100000 nodes,
// E=1.6M edges. All fp32.
//
// Pipeline per conv layer:
//   H = X @ W                      (gemm128_kernel, optional relu on input load)
//   acc = b + dinv^2 * H           (init_acc_kernel  — self-loop + bias, no atomics)
//   acc[dst] += H[src]*dinv[s]*dinv[d]  (scatter_kernel — fp32 atomics)
// relu is applied when acc is consumed (next GEMM / FC head).

#define NODE_F 128

__global__ void deg_kernel(const int* __restrict__ dst, float* __restrict__ deg, int E) {
    int i = blockIdx.x * blockDim.x + threadIdx.x;
    if (i < E) atomicAdd(&deg[dst[i]], 1.0f);
}

__global__ void dinv_kernel(float* __restrict__ deg, int N) {
    int i = blockIdx.x * blockDim.x + threadIdx.x;
    if (i < N) deg[i] = rsqrtf(deg[i] + 1.0f);   // +1 = self-loop
}

// H[N,128] = (relu?)X[N,128] @ W[128,128]
// block 256 threads computes a 64-row x 128-col tile; per thread 8 rows x 4 cols.
template<bool RELU_IN>
__global__ __launch_bounds__(256) void gemm128_kernel(
    const float* __restrict__ X, const float* __restrict__ W,
    float* __restrict__ H, int N)
{
    __shared__ float ws[32][128];   // W k-chunk
    __shared__ float xs[32][72];    // X k-chunk, transposed: xs[k][row]; stride 72 keeps 16B align

    const int tid = threadIdx.x;
    const int tc  = tid & 31;       // col quad: cols 4*tc .. 4*tc+3
    const int tr  = tid >> 5;       // row group: rows rbase + tr*8 .. +7
    const int rbase = blockIdx.x * 64;

    float acc[8][4];
    #pragma unroll
    for (int r = 0; r < 8; ++r)
        for (int c = 0; c < 4; ++c) acc[r][c] = 0.f;

    for (int kc = 0; kc < 128; kc += 32) {
        // stage W chunk: contiguous 16KB
        {
            const float4* Wv = reinterpret_cast<const float4*>(W + kc * 128);
            float4* wsv = reinterpret_cast<float4*>(&ws[0][0]);
            #pragma unroll
            for (int i = 0; i < 4; ++i)
                wsv[i * 256 + tid] = Wv[i * 256 + tid];
        }
        // stage X chunk transposed
        #pragma unroll
        for (int i = 0; i < 2; ++i) {
            int idx = i * 256 + tid;        // 0..511
            int r   = idx >> 3;             // 0..63
            int c4  = idx & 7;              // float4 within 32-wide chunk
            int row = rbase + r;
            float4 v = make_float4(0.f, 0.f, 0.f, 0.f);
            if (row < N)
                v = *reinterpret_cast<const float4*>(X + (size_t)row * NODE_F + kc + c4 * 4);
            if (RELU_IN) {
                v.x = fmaxf(v.x, 0.f); v.y = fmaxf(v.y, 0.f);
                v.z = fmaxf(v.z, 0.f); v.w = fmaxf(v.w, 0.f);
            }
            xs[c4 * 4 + 0][r] = v.x;
            xs[c4 * 4 + 1][r] = v.y;
            xs[c4 * 4 + 2][r] = v.z;
            xs[c4 * 4 + 3][r] = v.w;
        }
        __syncthreads();

        #pragma unroll
        for (int k = 0; k < 32; ++k) {
            float4 wv = *reinterpret_cast<const float4*>(&ws[k][tc * 4]);
            float4 x0 = *reinterpret_cast<const float4*>(&xs[k][tr * 8]);
            float4 x1 = *reinterpret_cast<const float4*>(&xs[k][tr * 8 + 4]);
            float xr[8] = {x0.x, x0.y, x0.z, x0.w, x1.x, x1.y, x1.z, x1.w};
            #pragma unroll
            for (int r = 0; r < 8; ++r) {
                acc[r][0] += xr[r] * wv.x;
                acc[r][1] += xr[r] * wv.y;
                acc[r][2] += xr[r] * wv.z;
                acc[r][3] += xr[r] * wv.w;
            }
        }
        __syncthreads();
    }

    #pragma unroll
    for (int r = 0; r < 8; ++r) {
        int row = rbase + tr * 8 + r;
        if (row < N)
            *reinterpret_cast<float4*>(H + (size_t)row * NODE_F + tc * 4) =
                make_float4(acc[r][0], acc[r][1], acc[r][2], acc[r][3]);
    }
}

// acc[i][f] = b[f] + dinv[i]^2 * H[i][f]
__global__ void init_acc_kernel(const float* __restrict__ H, const float* __restrict__ dinv,
                                const float* __restrict__ b, float* __restrict__ acc, int N)
{
    int i = blockIdx.x * blockDim.x + threadIdx.x;   // over N*32 float4s
    if (i >= N * 32) return;
    int row = i >> 5, q = i & 31;
    float dd = dinv[row];
    dd *= dd;
    float4 h  = reinterpret_cast<const float4*>(H)[i];
    float4 bb = reinterpret_cast<const float4*>(b)[q];
    float4 o;
    o.x = bb.x + dd * h.x;
    o.y = bb.y + dd * h.y;
    o.z = bb.z + dd * h.z;
    o.w = bb.w + dd * h.w;
    reinterpret_cast<float4*>(acc)[i] = o;
}

// acc[dst] += H[src] * dinv[src]*dinv[dst]; 32 threads (one float4 each) per edge
__global__ void scatter_kernel(const float* __restrict__ H, const int* __restrict__ src,
                               const int* __restrict__ dst, const float* __restrict__ dinv,
                               float* __restrict__ acc, int E)
{
    int gid = blockIdx.x * blockDim.x + threadIdx.x;
    int e = gid >> 5;
    if (e >= E) return;
    int q = gid & 31;
    int s = src[e], d = dst[e];
    float nrm = dinv[s] * dinv[d];
    float4 v = reinterpret_cast<const float4*>(H + (size_t)s * NODE_F)[q];
    float* a = acc + (size_t)d * NODE_F + q * 4;
    atomicAdd(a + 0, v.x * nrm);
    atomicAdd(a + 1, v.y * nrm);
    atomicAdd(a + 2, v.z * nrm);
    atomicAdd(a + 3, v.w * nrm);
}

// out[row][c] = tanh(bfc[c] + sum_k relu(A[row][k]) * Wfc[k][c]), one wave per row
__global__ __launch_bounds__(256) void fc_kernel(const float* __restrict__ A,
                                                 const float* __restrict__ Wfc,
                                                 const float* __restrict__ bfc,
                                                 float* __restrict__ out, int N)
{
    int wid  = (blockIdx.x * blockDim.x + threadIdx.x) >> 6;
    int lane = threadIdx.x & 63;
    if (wid >= N) return;
    const float* row = A + (size_t)wid * NODE_F;
    float a0 = fmaxf(row[lane], 0.f);
    float a1 = fmaxf(row[lane + 64], 0.f);
    float p0 = a0 * Wfc[lane * 3 + 0] + a1 * Wfc[(lane + 64) * 3 + 0];
    float p1 = a0 * Wfc[lane * 3 + 1] + a1 * Wfc[(lane + 64) * 3 + 1];
    float p2 = a0 * Wfc[lane * 3 + 2] + a1 * Wfc[(lane + 64) * 3 + 2];
    #pragma unroll
    for (int off = 32; off > 0; off >>= 1) {
        p0 += __shfl_down(p0, off);
        p1 += __shfl_down(p1, off);
        p2 += __shfl_down(p2, off);
    }
    if (lane == 0) {
        out[(size_t)wid * 3 + 0] = tanhf(p0 + bfc[0]);
        out[(size_t)wid * 3 + 1] = tanhf(p1 + bfc[1]);
        out[(size_t)wid * 3 + 2] = tanhf(p2 + bfc[2]);
    }
}

extern "C" void kernel_launch(void* const* d_in, const int* in_sizes, int n_in,
                              void* d_out, int out_size, void* d_ws, size_t ws_size,
                              hipStream_t stream)
{
    const float* x    = (const float*)d_in[0];
    const int*   edge = (const int*)d_in[1];
    const float* W1   = (const float*)d_in[2];
    const float* b1   = (const float*)d_in[3];
    const float* W2   = (const float*)d_in[4];
    const float* b2   = (const float*)d_in[5];
    const float* Wfc  = (const float*)d_in[6];
    const float* bfc  = (const float*)d_in[7];
    float* out = (float*)d_out;

    const int N = in_sizes[0] / NODE_F;
    const int E = in_sizes[1] / 2;
    const int* src = edge;
    const int* dst = edge + E;

    // workspace layout
    char* ws = (char*)d_ws;
    size_t off = 0;
    float* dinv = (float*)(ws + off); off += ((size_t)N * 4 + 511) & ~511ull;
    float* H    = (float*)(ws + off); off += (size_t)N * NODE_F * 4;
    float* acc  = (float*)(ws + off); off += (size_t)N * NODE_F * 4;
    (void)ws_size; (void)n_in; (void)out_size;

    const int B = 256;
    // degree + dinv
    hipMemsetAsync(dinv, 0, (size_t)N * sizeof(float), stream);
    deg_kernel<<<(E + B - 1) / B, B, 0, stream>>>(dst, dinv, E);
    dinv_kernel<<<(N + B - 1) / B, B, 0, stream>>>(dinv, N);

    int gemm_grid = (N + 63) / 64;
    int vec_grid  = (N * 32 + B - 1) / B;
    int sc_grid   = (E * 32 + B - 1) / B;   // E*32 = 51.2M threads, fits int

    // layer 1
    gemm128_kernel<false><<<gemm_grid, B, 0, stream>>>(x, W1, H, N);
    init_acc_kernel<<<vec_grid, B, 0, stream>>>(H, dinv, b1, acc, N);
    scatter_kernel<<<sc_grid, B, 0, stream>>>(H, src, dst, dinv, acc, E);

    // layer 2 (relu applied on load of acc)
    gemm128_kernel<true><<<gemm_grid, B, 0, stream>>>(acc, W2, H, N);
    init_acc_kernel<<<vec_grid, B, 0, stream>>>(H, dinv, b2, acc, N);
    scatter_kernel<<<sc_grid, B, 0, stream>>>(H, src, dst, dinv, acc, E);

    // FC head: one wave per row
    fc_kernel<<<(N + 3) / 4, B, 0, stream>>>(acc, Wfc, bfc, out, N);
}

// Round 2
// 647.950 us; speedup vs baseline: 8.6273x; 8.6273x over previous
//
#include <hip/hip_runtime.h>
#include <hip/hip_bf16.h>

// ResidualGNN: 2x GCNConv(128->128, relu) + FC(128->3, tanh), N=100000, E=1.6M, fp32.
//
// Round 1: replace fp32-atomic scatter (2x2680us, atomic-bound) with CSR-by-dst
// build + register-accumulating gather (one wave per node, single write per row).

#define NODE_F 128

// ---- CSR build ----------------------------------------------------------

__global__ void deg_count_kernel(const int* __restrict__ dst, int* __restrict__ degE, int E) {
    int i = blockIdx.x * blockDim.x + threadIdx.x;
    if (i < E) atomicAdd(&degE[dst[i]], 1);
}

__global__ void dinv_kernel(const int* __restrict__ degE, float* __restrict__ dinv, int N) {
    int i = blockIdx.x * blockDim.x + threadIdx.x;
    if (i < N) dinv[i] = rsqrtf((float)degE[i] + 1.0f);   // +1 = self-loop
}

// single-block exclusive prefix scan: row_start[0..N] over degE[0..N-1]
__global__ __launch_bounds__(1024) void scan_kernel(const int* __restrict__ degE,
                                                    int* __restrict__ row_start, int N)
{
    __shared__ int sums[1024];
    __shared__ int carry_s;
    const int tid = threadIdx.x;
    if (tid == 0) carry_s = 0;
    __syncthreads();
    for (int base = 0; base < N; base += 4096) {
        int idx = base + tid * 4;
        int v[4];
        #pragma unroll
        for (int j = 0; j < 4; ++j)
            v[j] = (idx + j < N) ? degE[idx + j] : 0;
        int t = v[0] + v[1] + v[2] + v[3];
        sums[tid] = t;
        __syncthreads();
        #pragma unroll
        for (int off = 1; off < 1024; off <<= 1) {
            int x = (tid >= off) ? sums[tid - off] : 0;
            __syncthreads();
            sums[tid] += x;
            __syncthreads();
        }
        int excl = sums[tid] - t + carry_s;
        #pragma unroll
        for (int j = 0; j < 4; ++j) {
            if (idx + j <= N) row_start[idx + j] = excl;
            excl += v[j];
        }
        __syncthreads();
        if (tid == 1023) carry_s += sums[1023];
        __syncthreads();
    }
}

__global__ void fill_kernel(const int* __restrict__ src, const int* __restrict__ dst,
                            const int* __restrict__ row_start, int* __restrict__ cursor,
                            int* __restrict__ csr_src, int E)
{
    int e = blockIdx.x * blockDim.x + threadIdx.x;
    if (e >= E) return;
    int d = dst[e];
    int pos = atomicAdd(&cursor[d], 1);
    csr_src[row_start[d] + pos] = src[e];
}

// ---- GEMM: H[N,128] = (relu?)X[N,128] @ W[128,128] ----------------------

template<bool RELU_IN>
__global__ __launch_bounds__(256) void gemm128_kernel(
    const float* __restrict__ X, const float* __restrict__ W,
    float* __restrict__ H, int N)
{
    __shared__ float ws[32][128];
    __shared__ float xs[32][72];

    const int tid = threadIdx.x;
    const int tc  = tid & 31;
    const int tr  = tid >> 5;
    const int rbase = blockIdx.x * 64;

    float acc[8][4];
    #pragma unroll
    for (int r = 0; r < 8; ++r)
        for (int c = 0; c < 4; ++c) acc[r][c] = 0.f;

    for (int kc = 0; kc < 128; kc += 32) {
        {
            const float4* Wv = reinterpret_cast<const float4*>(W + kc * 128);
            float4* wsv = reinterpret_cast<float4*>(&ws[0][0]);
            #pragma unroll
            for (int i = 0; i < 4; ++i)
                wsv[i * 256 + tid] = Wv[i * 256 + tid];
        }
        #pragma unroll
        for (int i = 0; i < 2; ++i) {
            int idx = i * 256 + tid;
            int r   = idx >> 3;
            int c4  = idx & 7;
            int row = rbase + r;
            float4 v = make_float4(0.f, 0.f, 0.f, 0.f);
            if (row < N)
                v = *reinterpret_cast<const float4*>(X + (size_t)row * NODE_F + kc + c4 * 4);
            if (RELU_IN) {
                v.x = fmaxf(v.x, 0.f); v.y = fmaxf(v.y, 0.f);
                v.z = fmaxf(v.z, 0.f); v.w = fmaxf(v.w, 0.f);
            }
            xs[c4 * 4 + 0][r] = v.x;
            xs[c4 * 4 + 1][r] = v.y;
            xs[c4 * 4 + 2][r] = v.z;
            xs[c4 * 4 + 3][r] = v.w;
        }
        __syncthreads();

        #pragma unroll
        for (int k = 0; k < 32; ++k) {
            float4 wv = *reinterpret_cast<const float4*>(&ws[k][tc * 4]);
            float4 x0 = *reinterpret_cast<const float4*>(&xs[k][tr * 8]);
            float4 x1 = *reinterpret_cast<const float4*>(&xs[k][tr * 8 + 4]);
            float xr[8] = {x0.x, x0.y, x0.z, x0.w, x1.x, x1.y, x1.z, x1.w};
            #pragma unroll
            for (int r = 0; r < 8; ++r) {
                acc[r][0] += xr[r] * wv.x;
                acc[r][1] += xr[r] * wv.y;
                acc[r][2] += xr[r] * wv.z;
                acc[r][3] += xr[r] * wv.w;
            }
        }
        __syncthreads();
    }

    #pragma unroll
    for (int r = 0; r < 8; ++r) {
        int row = rbase + tr * 8 + r;
        if (row < N)
            *reinterpret_cast<float4*>(H + (size_t)row * NODE_F + tc * 4) =
                make_float4(acc[r][0], acc[r][1], acc[r][2], acc[r][3]);
    }
}

// ---- gather: acc[d] = b + dinv[d]^2*H[d] + sum_{s in in(d)} dinv[s]dinv[d] H[s]
// one wave per node; lane owns a float2 (2 of 128 features).
__global__ __launch_bounds__(256) void gather_kernel(
    const float* __restrict__ H, const int* __restrict__ csr_src,
    const int* __restrict__ row_start, const float* __restrict__ dinv,
    const float* __restrict__ b, float* __restrict__ acc, int N)
{
    int node = (blockIdx.x * blockDim.x + threadIdx.x) >> 6;
    int lane = threadIdx.x & 63;
    if (node >= N) return;

    const float2* H2 = reinterpret_cast<const float2*>(H);
    const float dd = dinv[node];
    float2 bb = reinterpret_cast<const float2*>(b)[lane];
    float2 h0 = H2[(size_t)node * 64 + lane];
    float2 a;
    a.x = bb.x + dd * dd * h0.x;
    a.y = bb.y + dd * dd * h0.y;

    int i   = row_start[node];
    int end = row_start[node + 1];
    for (; i + 1 < end; i += 2) {
        int s0 = csr_src[i], s1 = csr_src[i + 1];
        float n0 = dinv[s0] * dd;
        float n1 = dinv[s1] * dd;
        float2 v0 = H2[(size_t)s0 * 64 + lane];
        float2 v1 = H2[(size_t)s1 * 64 + lane];
        a.x += v0.x * n0 + v1.x * n1;
        a.y += v0.y * n0 + v1.y * n1;
    }
    if (i < end) {
        int s = csr_src[i];
        float nrm = dinv[s] * dd;
        float2 v = H2[(size_t)s * 64 + lane];
        a.x += v.x * nrm;
        a.y += v.y * nrm;
    }
    reinterpret_cast<float2*>(acc)[(size_t)node * 64 + lane] = a;
}

// ---- FC head: out = tanh(relu(A) @ Wfc + bfc), one wave per row ---------

__global__ __launch_bounds__(256) void fc_kernel(const float* __restrict__ A,
                                                 const float* __restrict__ Wfc,
                                                 const float* __restrict__ bfc,
                                                 float* __restrict__ out, int N)
{
    int wid  = (blockIdx.x * blockDim.x + threadIdx.x) >> 6;
    int lane = threadIdx.x & 63;
    if (wid >= N) return;
    const float* row = A + (size_t)wid * NODE_F;
    float a0 = fmaxf(row[lane], 0.f);
    float a1 = fmaxf(row[lane + 64], 0.f);
    float p0 = a0 * Wfc[lane * 3 + 0] + a1 * Wfc[(lane + 64) * 3 + 0];
    float p1 = a0 * Wfc[lane * 3 + 1] + a1 * Wfc[(lane + 64) * 3 + 1];
    float p2 = a0 * Wfc[lane * 3 + 2] + a1 * Wfc[(lane + 64) * 3 + 2];
    #pragma unroll
    for (int off = 32; off > 0; off >>= 1) {
        p0 += __shfl_down(p0, off);
        p1 += __shfl_down(p1, off);
        p2 += __shfl_down(p2, off);
    }
    if (lane == 0) {
        out[(size_t)wid * 3 + 0] = tanhf(p0 + bfc[0]);
        out[(size_t)wid * 3 + 1] = tanhf(p1 + bfc[1]);
        out[(size_t)wid * 3 + 2] = tanhf(p2 + bfc[2]);
    }
}

extern "C" void kernel_launch(void* const* d_in, const int* in_sizes, int n_in,
                              void* d_out, int out_size, void* d_ws, size_t ws_size,
                              hipStream_t stream)
{
    const float* x    = (const float*)d_in[0];
    const int*   edge = (const int*)d_in[1];
    const float* W1   = (const float*)d_in[2];
    const float* b1   = (const float*)d_in[3];
    const float* W2   = (const float*)d_in[4];
    const float* b2   = (const float*)d_in[5];
    const float* Wfc  = (const float*)d_in[6];
    const float* bfc  = (const float*)d_in[7];
    float* out = (float*)d_out;

    const int N = in_sizes[0] / NODE_F;
    const int E = in_sizes[1] / 2;
    const int* src = edge;
    const int* dst = edge + E;

    // workspace layout (~110.5 MB)
    char* ws = (char*)d_ws;
    size_t off = 0;
    auto alloc = [&](size_t bytes) {
        void* p = ws + off;
        off += (bytes + 511) & ~511ull;
        return p;
    };
    float* dinv      = (float*)alloc((size_t)N * 4);
    int*   degE      = (int*)  alloc((size_t)N * 4);
    int*   cursor    = (int*)  alloc((size_t)N * 4);
    int*   row_start = (int*)  alloc((size_t)(N + 1) * 4);
    int*   csr_src   = (int*)  alloc((size_t)E * 4);
    float* H         = (float*)alloc((size_t)N * NODE_F * 4);
    float* acc       = (float*)alloc((size_t)N * NODE_F * 4);
    (void)ws_size; (void)n_in; (void)out_size;

    const int B = 256;

    // CSR build
    hipMemsetAsync(degE,   0, (size_t)N * 4, stream);
    hipMemsetAsync(cursor, 0, (size_t)N * 4, stream);
    deg_count_kernel<<<(E + B - 1) / B, B, 0, stream>>>(dst, degE, E);
    dinv_kernel<<<(N + B - 1) / B, B, 0, stream>>>(degE, dinv, N);
    scan_kernel<<<1, 1024, 0, stream>>>(degE, row_start, N);
    fill_kernel<<<(E + B - 1) / B, B, 0, stream>>>(src, dst, row_start, cursor, csr_src, E);

    int gemm_grid   = (N + 63) / 64;
    int gather_grid = (N + 3) / 4;   // 4 waves per block

    // layer 1
    gemm128_kernel<false><<<gemm_grid, B, 0, stream>>>(x, W1, H, N);
    gather_kernel<<<gather_grid, B, 0, stream>>>(H, csr_src, row_start, dinv, b1, acc, N);

    // layer 2 (relu on load)
    gemm128_kernel<true><<<gemm_grid, B, 0, stream>>>(acc, W2, H, N);
    gather_kernel<<<gather_grid, B, 0, stream>>>(H, csr_src, row_start, dinv, b2, acc, N);

    // FC head
    fc_kernel<<<(N + 3) / 4, B, 0, stream>>>(acc, Wfc, bfc, out, N);
}

// Round 3
// 569.250 us; speedup vs baseline: 9.8200x; 1.1383x over previous
//
#include <hip/hip_runtime.h>
#include <hip/hip_bf16.h>

// ResidualGNN: 2x GCNConv(128->128, relu) + FC(128->3, tanh), N=100000, E=1.6M, fp32.
// R2: parallel scan, split-bf16 MFMA GEMM (3-product, ~2^-16 rel err), gather unroll4.

#define NODE_F 128

typedef __attribute__((ext_vector_type(8))) short bf16x8;
typedef __attribute__((ext_vector_type(4))) float f32x4;

__device__ inline unsigned short bf16_rn(float x) {
    unsigned u = __builtin_bit_cast(unsigned, x);
    unsigned r = (u + 0x7fffu + ((u >> 16) & 1u)) >> 16;
    return (unsigned short)r;
}
__device__ inline float bf16_to_f(unsigned short h) {
    unsigned u = (unsigned)h << 16;
    return __builtin_bit_cast(float, u);
}

// ---- CSR build ----------------------------------------------------------

__global__ void deg_count_kernel(const int* __restrict__ dst, int* __restrict__ degE, int E) {
    int i = blockIdx.x * blockDim.x + threadIdx.x;
    if (i < E) atomicAdd(&degE[dst[i]], 1);
}

// per-1024-chunk exclusive scan; block sums out
__global__ __launch_bounds__(256) void scan_block_kernel(
    const int* __restrict__ degE, int* __restrict__ row_start,
    int* __restrict__ bsum, int N)
{
    __shared__ int s[256];
    const int tid = threadIdx.x;
    const int idx = blockIdx.x * 1024 + tid * 4;
    int v0 = (idx + 0 < N) ? degE[idx + 0] : 0;
    int v1 = (idx + 1 < N) ? degE[idx + 1] : 0;
    int v2 = (idx + 2 < N) ? degE[idx + 2] : 0;
    int v3 = (idx + 3 < N) ? degE[idx + 3] : 0;
    int t = v0 + v1 + v2 + v3;
    s[tid] = t;
    __syncthreads();
    #pragma unroll
    for (int off = 1; off < 256; off <<= 1) {
        int x = (tid >= off) ? s[tid - off] : 0;
        __syncthreads();
        s[tid] += x;
        __syncthreads();
    }
    int excl = s[tid] - t;
    if (idx + 0 < N) row_start[idx + 0] = excl;
    if (idx + 1 < N) row_start[idx + 1] = excl + v0;
    if (idx + 2 < N) row_start[idx + 2] = excl + v0 + v1;
    if (idx + 3 < N) row_start[idx + 3] = excl + v0 + v1 + v2;
    if (tid == 255) bsum[blockIdx.x] = s[255];
}

// exclusive scan of block sums (nb <= 1024), in place
__global__ __launch_bounds__(1024) void scan_tops_kernel(int* __restrict__ bsum, int nb) {
    __shared__ int s[1024];
    const int tid = threadIdx.x;
    int v = (tid < nb) ? bsum[tid] : 0;
    s[tid] = v;
    __syncthreads();
    #pragma unroll
    for (int off = 1; off < 1024; off <<= 1) {
        int x = (tid >= off) ? s[tid - off] : 0;
        __syncthreads();
        s[tid] += x;
        __syncthreads();
    }
    if (tid < nb) bsum[tid] = s[tid] - v;
}

// add block offsets; compute dinv; write row_start[N]
__global__ void scan_finish_kernel(const int* __restrict__ degE, int* __restrict__ row_start,
                                   const int* __restrict__ bsum, float* __restrict__ dinv, int N)
{
    int i = blockIdx.x * blockDim.x + threadIdx.x;
    if (i >= N) return;
    int rs = row_start[i] + bsum[i >> 10];
    row_start[i] = rs;
    dinv[i] = rsqrtf((float)degE[i] + 1.0f);
    if (i == N - 1) row_start[N] = rs + degE[i];
}

__global__ void fill_kernel(const int* __restrict__ src, const int* __restrict__ dst,
                            const int* __restrict__ row_start, int* __restrict__ cursor,
                            int* __restrict__ csr_src, int E)
{
    int e = blockIdx.x * blockDim.x + threadIdx.x;
    if (e >= E) return;
    int d = dst[e];
    int pos = atomicAdd(&cursor[d], 1);
    csr_src[row_start[d] + pos] = src[e];
}

// ---- W -> bf16 hi/lo, transposed to [n][k] ------------------------------

__global__ __launch_bounds__(256) void wconv_kernel(const float* __restrict__ W,
                                                    unsigned short* __restrict__ WhiT,
                                                    unsigned short* __restrict__ WloT)
{
    int tid = threadIdx.x;
    for (int i = tid; i < 128 * 128; i += 256) {
        int k = i >> 7, n = i & 127;
        float x = W[i];
        unsigned short hi = bf16_rn(x);
        float lo = x - bf16_to_f(hi);
        WhiT[n * 128 + k] = hi;
        WloT[n * 128 + k] = bf16_rn(lo);
    }
}

// ---- GEMM: H[N,128] = (relu?)X[N,128] @ W[128,128] via split-bf16 MFMA --
// block: 64 rows x 128 cols, 4 waves; wave w owns cols w*32..w*32+31.

template<bool RELU_IN>
__global__ __launch_bounds__(256) void gemm_mfma_kernel(
    const float* __restrict__ X, const unsigned short* __restrict__ WhiT,
    const unsigned short* __restrict__ WloT, float* __restrict__ H, int N)
{
    __shared__ unsigned short xhi[64 * 128];   // [row][k], XOR-swizzled
    __shared__ unsigned short xlo[64 * 128];

    const int tid  = threadIdx.x;
    const int lane = tid & 63;
    const int w    = tid >> 6;
    const int rbase = blockIdx.x * 64;

    // preload all B fragments (W^T), 2 n-tiles x 4 k-steps x {hi,lo}
    bf16x8 bhi[2][4], blo[2][4];
    {
        int n0   = w * 32 + (lane & 15);
        int koct = (lane >> 4) * 8;
        #pragma unroll
        for (int nt = 0; nt < 2; ++nt) {
            #pragma unroll
            for (int kk = 0; kk < 4; ++kk) {
                size_t o = (size_t)(n0 + nt * 16) * 128 + kk * 32 + koct;
                bhi[nt][kk] = *reinterpret_cast<const bf16x8*>(WhiT + o);
                blo[nt][kk] = *reinterpret_cast<const bf16x8*>(WloT + o);
            }
        }
    }

    // stage X tile (64x128 fp32) -> hi/lo bf16 LDS, swizzled byte = row*256 + (kbyte ^ ((row&7)<<4))
    #pragma unroll
    for (int it = 0; it < 8; ++it) {
        int f   = it * 256 + tid;     // float4 index 0..2047
        int row = f >> 5;
        int k4  = f & 31;
        float4 v = make_float4(0.f, 0.f, 0.f, 0.f);
        if (rbase + row < N)
            v = *reinterpret_cast<const float4*>(X + (size_t)(rbase + row) * NODE_F + k4 * 4);
        if (RELU_IN) {
            v.x = fmaxf(v.x, 0.f); v.y = fmaxf(v.y, 0.f);
            v.z = fmaxf(v.z, 0.f); v.w = fmaxf(v.w, 0.f);
        }
        float xs[4] = {v.x, v.y, v.z, v.w};
        ushort4 h4, l4;
        unsigned short* hp = &h4.x;
        unsigned short* lp = &l4.x;
        #pragma unroll
        for (int j = 0; j < 4; ++j) {
            unsigned short hi = bf16_rn(xs[j]);
            hp[j] = hi;
            lp[j] = bf16_rn(xs[j] - bf16_to_f(hi));
        }
        int byte = row * 256 + ((k4 * 8) ^ ((row & 7) << 4));
        *reinterpret_cast<ushort4*>(reinterpret_cast<char*>(xhi) + byte) = h4;
        *reinterpret_cast<ushort4*>(reinterpret_cast<char*>(xlo) + byte) = l4;
    }
    __syncthreads();

    f32x4 acc[4][2];
    #pragma unroll
    for (int m = 0; m < 4; ++m)
        #pragma unroll
        for (int nt = 0; nt < 2; ++nt)
            acc[m][nt] = (f32x4){0.f, 0.f, 0.f, 0.f};

    #pragma unroll
    for (int kk = 0; kk < 4; ++kk) {
        #pragma unroll
        for (int m = 0; m < 4; ++m) {
            int row  = m * 16 + (lane & 15);
            int koff = kk * 64 + (lane >> 4) * 16;          // bytes within row
            int byte = row * 256 + (koff ^ ((row & 7) << 4));
            bf16x8 ahi = *reinterpret_cast<const bf16x8*>(reinterpret_cast<char*>(xhi) + byte);
            bf16x8 alo = *reinterpret_cast<const bf16x8*>(reinterpret_cast<char*>(xlo) + byte);
            #pragma unroll
            for (int nt = 0; nt < 2; ++nt) {
                acc[m][nt] = __builtin_amdgcn_mfma_f32_16x16x32_bf16(ahi, bhi[nt][kk], acc[m][nt], 0, 0, 0);
                acc[m][nt] = __builtin_amdgcn_mfma_f32_16x16x32_bf16(ahi, blo[nt][kk], acc[m][nt], 0, 0, 0);
                acc[m][nt] = __builtin_amdgcn_mfma_f32_16x16x32_bf16(alo, bhi[nt][kk], acc[m][nt], 0, 0, 0);
            }
        }
    }

    // epilogue: D col = lane&15, row = (lane>>4)*4 + r   [m89-verified layout]
    #pragma unroll
    for (int m = 0; m < 4; ++m) {
        int row = rbase + m * 16 + (lane >> 4) * 4;
        int col = w * 32 + (lane & 15);
        #pragma unroll
        for (int nt = 0; nt < 2; ++nt) {
            #pragma unroll
            for (int r = 0; r < 4; ++r) {
                if (row + r < N)
                    H[(size_t)(row + r) * NODE_F + col + nt * 16] = acc[m][nt][r];
            }
        }
    }
}

// ---- gather: acc[d] = b + dinv[d]^2*H[d] + sum_{s in in(d)} dinv[s]dinv[d] H[s]
__global__ __launch_bounds__(256) void gather_kernel(
    const float* __restrict__ H, const int* __restrict__ csr_src,
    const int* __restrict__ row_start, const float* __restrict__ dinv,
    const float* __restrict__ b, float* __restrict__ acc, int N)
{
    int node = (blockIdx.x * blockDim.x + threadIdx.x) >> 6;
    int lane = threadIdx.x & 63;
    if (node >= N) return;

    const float2* H2 = reinterpret_cast<const float2*>(H);
    const float dd = dinv[node];
    float2 bb = reinterpret_cast<const float2*>(b)[lane];
    float2 h0 = H2[(size_t)node * 64 + lane];
    float2 a;
    a.x = bb.x + dd * dd * h0.x;
    a.y = bb.y + dd * dd * h0.y;

    int i   = row_start[node];
    int end = row_start[node + 1];
    for (; i + 3 < end; i += 4) {
        int s0 = csr_src[i], s1 = csr_src[i + 1], s2 = csr_src[i + 2], s3 = csr_src[i + 3];
        float n0 = dinv[s0] * dd, n1 = dinv[s1] * dd;
        float n2 = dinv[s2] * dd, n3 = dinv[s3] * dd;
        float2 v0 = H2[(size_t)s0 * 64 + lane];
        float2 v1 = H2[(size_t)s1 * 64 + lane];
        float2 v2 = H2[(size_t)s2 * 64 + lane];
        float2 v3 = H2[(size_t)s3 * 64 + lane];
        a.x += v0.x * n0 + v1.x * n1 + v2.x * n2 + v3.x * n3;
        a.y += v0.y * n0 + v1.y * n1 + v2.y * n2 + v3.y * n3;
    }
    for (; i < end; ++i) {
        int s = csr_src[i];
        float nrm = dinv[s] * dd;
        float2 v = H2[(size_t)s * 64 + lane];
        a.x += v.x * nrm;
        a.y += v.y * nrm;
    }
    reinterpret_cast<float2*>(acc)[(size_t)node * 64 + lane] = a;
}

// ---- FC head: out = tanh(relu(A) @ Wfc + bfc), one wave per row ---------

__global__ __launch_bounds__(256) void fc_kernel(const float* __restrict__ A,
                                                 const float* __restrict__ Wfc,
                                                 const float* __restrict__ bfc,
                                                 float* __restrict__ out, int N)
{
    int wid  = (blockIdx.x * blockDim.x + threadIdx.x) >> 6;
    int lane = threadIdx.x & 63;
    if (wid >= N) return;
    const float* row = A + (size_t)wid * NODE_F;
    float a0 = fmaxf(row[lane], 0.f);
    float a1 = fmaxf(row[lane + 64], 0.f);
    float p0 = a0 * Wfc[lane * 3 + 0] + a1 * Wfc[(lane + 64) * 3 + 0];
    float p1 = a0 * Wfc[lane * 3 + 1] + a1 * Wfc[(lane + 64) * 3 + 1];
    float p2 = a0 * Wfc[lane * 3 + 2] + a1 * Wfc[(lane + 64) * 3 + 2];
    #pragma unroll
    for (int off = 32; off > 0; off >>= 1) {
        p0 += __shfl_down(p0, off);
        p1 += __shfl_down(p1, off);
        p2 += __shfl_down(p2, off);
    }
    if (lane == 0) {
        out[(size_t)wid * 3 + 0] = tanhf(p0 + bfc[0]);
        out[(size_t)wid * 3 + 1] = tanhf(p1 + bfc[1]);
        out[(size_t)wid * 3 + 2] = tanhf(p2 + bfc[2]);
    }
}

extern "C" void kernel_launch(void* const* d_in, const int* in_sizes, int n_in,
                              void* d_out, int out_size, void* d_ws, size_t ws_size,
                              hipStream_t stream)
{
    const float* x    = (const float*)d_in[0];
    const int*   edge = (const int*)d_in[1];
    const float* W1   = (const float*)d_in[2];
    const float* b1   = (const float*)d_in[3];
    const float* W2   = (const float*)d_in[4];
    const float* b2   = (const float*)d_in[5];
    const float* Wfc  = (const float*)d_in[6];
    const float* bfc  = (const float*)d_in[7];
    float* out = (float*)d_out;

    const int N = in_sizes[0] / NODE_F;
    const int E = in_sizes[1] / 2;
    const int* src = edge;
    const int* dst = edge + E;

    char* ws = (char*)d_ws;
    size_t off = 0;
    auto alloc = [&](size_t bytes) {
        void* p = ws + off;
        off += (bytes + 511) & ~511ull;
        return p;
    };
    const int nblk1024 = (N + 1023) / 1024;
    float* dinv      = (float*)alloc((size_t)N * 4);
    int*   degE      = (int*)  alloc((size_t)N * 4);
    int*   cursor    = (int*)  alloc((size_t)N * 4);
    int*   row_start = (int*)  alloc((size_t)(N + 1) * 4);
    int*   bsum      = (int*)  alloc((size_t)nblk1024 * 4);
    int*   csr_src   = (int*)  alloc((size_t)E * 4);
    unsigned short* W1hiT = (unsigned short*)alloc(128 * 128 * 2);
    unsigned short* W1loT = (unsigned short*)alloc(128 * 128 * 2);
    unsigned short* W2hiT = (unsigned short*)alloc(128 * 128 * 2);
    unsigned short* W2loT = (unsigned short*)alloc(128 * 128 * 2);
    float* H         = (float*)alloc((size_t)N * NODE_F * 4);
    float* acc       = (float*)alloc((size_t)N * NODE_F * 4);
    (void)ws_size; (void)n_in; (void)out_size;

    const int B = 256;

    // weight conversions (independent, tiny)
    wconv_kernel<<<1, B, 0, stream>>>(W1, W1hiT, W1loT);
    wconv_kernel<<<1, B, 0, stream>>>(W2, W2hiT, W2loT);

    // CSR build
    hipMemsetAsync(degE,   0, (size_t)N * 4, stream);
    hipMemsetAsync(cursor, 0, (size_t)N * 4, stream);
    deg_count_kernel<<<(E + B - 1) / B, B, 0, stream>>>(dst, degE, E);
    scan_block_kernel<<<nblk1024, B, 0, stream>>>(degE, row_start, bsum, N);
    scan_tops_kernel<<<1, 1024, 0, stream>>>(bsum, nblk1024);
    scan_finish_kernel<<<(N + B - 1) / B, B, 0, stream>>>(degE, row_start, bsum, dinv, N);
    fill_kernel<<<(E + B - 1) / B, B, 0, stream>>>(src, dst, row_start, cursor, csr_src, E);

    int gemm_grid   = (N + 63) / 64;
    int gather_grid = (N + 3) / 4;

    // layer 1
    gemm_mfma_kernel<false><<<gemm_grid, B, 0, stream>>>(x, W1hiT, W1loT, H, N);
    gather_kernel<<<gather_grid, B, 0, stream>>>(H, csr_src, row_start, dinv, b1, acc, N);

    // layer 2 (relu on load)
    gemm_mfma_kernel<true><<<gemm_grid, B, 0, stream>>>(acc, W2hiT, W2loT, H, N);
    gather_kernel<<<gather_grid, B, 0, stream>>>(H, csr_src, row_start, dinv, b2, acc, N);

    // FC head
    fc_kernel<<<(N + 3) / 4, B, 0, stream>>>(acc, Wfc, bfc, out, N);
}

// Round 4
// 428.899 us; speedup vs baseline: 13.0334x; 1.3272x over previous
//
#include <hip/hip_runtime.h>
#include <hip/hip_bf16.h>
#include <hip/hip_fp16.h>

// ResidualGNN: 2x GCNConv(128->128, relu) + FC(128->3, tanh), N=100000, E=1.6M, fp32.
// R3: H stored fp16 (halves gather read traffic + GEMM write traffic); merged wconv.

#define NODE_F 128

typedef __attribute__((ext_vector_type(8))) short bf16x8;
typedef __attribute__((ext_vector_type(4))) float f32x4;

__device__ inline unsigned short bf16_rn(float x) {
    unsigned u = __builtin_bit_cast(unsigned, x);
    unsigned r = (u + 0x7fffu + ((u >> 16) & 1u)) >> 16;
    return (unsigned short)r;
}
__device__ inline float bf16_to_f(unsigned short h) {
    unsigned u = (unsigned)h << 16;
    return __builtin_bit_cast(float, u);
}

// ---- CSR build ----------------------------------------------------------

__global__ void deg_count_kernel(const int* __restrict__ dst, int* __restrict__ degE, int E) {
    int i = blockIdx.x * blockDim.x + threadIdx.x;
    if (i < E) atomicAdd(&degE[dst[i]], 1);
}

__global__ __launch_bounds__(256) void scan_block_kernel(
    const int* __restrict__ degE, int* __restrict__ row_start,
    int* __restrict__ bsum, int N)
{
    __shared__ int s[256];
    const int tid = threadIdx.x;
    const int idx = blockIdx.x * 1024 + tid * 4;
    int v0 = (idx + 0 < N) ? degE[idx + 0] : 0;
    int v1 = (idx + 1 < N) ? degE[idx + 1] : 0;
    int v2 = (idx + 2 < N) ? degE[idx + 2] : 0;
    int v3 = (idx + 3 < N) ? degE[idx + 3] : 0;
    int t = v0 + v1 + v2 + v3;
    s[tid] = t;
    __syncthreads();
    #pragma unroll
    for (int off = 1; off < 256; off <<= 1) {
        int x = (tid >= off) ? s[tid - off] : 0;
        __syncthreads();
        s[tid] += x;
        __syncthreads();
    }
    int excl = s[tid] - t;
    if (idx + 0 < N) row_start[idx + 0] = excl;
    if (idx + 1 < N) row_start[idx + 1] = excl + v0;
    if (idx + 2 < N) row_start[idx + 2] = excl + v0 + v1;
    if (idx + 3 < N) row_start[idx + 3] = excl + v0 + v1 + v2;
    if (tid == 255) bsum[blockIdx.x] = s[255];
}

__global__ __launch_bounds__(1024) void scan_tops_kernel(int* __restrict__ bsum, int nb) {
    __shared__ int s[1024];
    const int tid = threadIdx.x;
    int v = (tid < nb) ? bsum[tid] : 0;
    s[tid] = v;
    __syncthreads();
    #pragma unroll
    for (int off = 1; off < 1024; off <<= 1) {
        int x = (tid >= off) ? s[tid - off] : 0;
        __syncthreads();
        s[tid] += x;
        __syncthreads();
    }
    if (tid < nb) bsum[tid] = s[tid] - v;
}

__global__ void scan_finish_kernel(const int* __restrict__ degE, int* __restrict__ row_start,
                                   const int* __restrict__ bsum, float* __restrict__ dinv, int N)
{
    int i = blockIdx.x * blockDim.x + threadIdx.x;
    if (i >= N) return;
    int rs = row_start[i] + bsum[i >> 10];
    row_start[i] = rs;
    dinv[i] = rsqrtf((float)degE[i] + 1.0f);
    if (i == N - 1) row_start[N] = rs + degE[i];
}

__global__ void fill_kernel(const int* __restrict__ src, const int* __restrict__ dst,
                            const int* __restrict__ row_start, int* __restrict__ cursor,
                            int* __restrict__ csr_src, int E)
{
    int e = blockIdx.x * blockDim.x + threadIdx.x;
    if (e >= E) return;
    int d = dst[e];
    int pos = atomicAdd(&cursor[d], 1);
    csr_src[row_start[d] + pos] = src[e];
}

// ---- W -> bf16 hi/lo, transposed to [n][k]; both weights in one launch --

__global__ __launch_bounds__(256) void wconv_kernel(const float* __restrict__ W1,
                                                    const float* __restrict__ W2,
                                                    unsigned short* __restrict__ WhiT,
                                                    unsigned short* __restrict__ WloT)
{
    const float* W = blockIdx.x ? W2 : W1;
    unsigned short* hiT = WhiT + blockIdx.x * 128 * 128;
    unsigned short* loT = WloT + blockIdx.x * 128 * 128;
    int tid = threadIdx.x;
    for (int i = tid; i < 128 * 128; i += 256) {
        int k = i >> 7, n = i & 127;
        float x = W[i];
        unsigned short hi = bf16_rn(x);
        float lo = x - bf16_to_f(hi);
        hiT[n * 128 + k] = hi;
        loT[n * 128 + k] = bf16_rn(lo);
    }
}

// ---- GEMM: Hh[N,128](fp16) = (relu?)X[N,128] @ W[128,128] via split-bf16 MFMA

template<bool RELU_IN>
__global__ __launch_bounds__(256) void gemm_mfma_kernel(
    const float* __restrict__ X, const unsigned short* __restrict__ WhiT,
    const unsigned short* __restrict__ WloT, __half* __restrict__ Hh, int N)
{
    __shared__ unsigned short xhi[64 * 128];   // [row][k], XOR-swizzled
    __shared__ unsigned short xlo[64 * 128];

    const int tid  = threadIdx.x;
    const int lane = tid & 63;
    const int w    = tid >> 6;
    const int rbase = blockIdx.x * 64;

    bf16x8 bhi[2][4], blo[2][4];
    {
        int n0   = w * 32 + (lane & 15);
        int koct = (lane >> 4) * 8;
        #pragma unroll
        for (int nt = 0; nt < 2; ++nt) {
            #pragma unroll
            for (int kk = 0; kk < 4; ++kk) {
                size_t o = (size_t)(n0 + nt * 16) * 128 + kk * 32 + koct;
                bhi[nt][kk] = *reinterpret_cast<const bf16x8*>(WhiT + o);
                blo[nt][kk] = *reinterpret_cast<const bf16x8*>(WloT + o);
            }
        }
    }

    #pragma unroll
    for (int it = 0; it < 8; ++it) {
        int f   = it * 256 + tid;
        int row = f >> 5;
        int k4  = f & 31;
        float4 v = make_float4(0.f, 0.f, 0.f, 0.f);
        if (rbase + row < N)
            v = *reinterpret_cast<const float4*>(X + (size_t)(rbase + row) * NODE_F + k4 * 4);
        if (RELU_IN) {
            v.x = fmaxf(v.x, 0.f); v.y = fmaxf(v.y, 0.f);
            v.z = fmaxf(v.z, 0.f); v.w = fmaxf(v.w, 0.f);
        }
        float xs[4] = {v.x, v.y, v.z, v.w};
        ushort4 h4, l4;
        unsigned short* hp = &h4.x;
        unsigned short* lp = &l4.x;
        #pragma unroll
        for (int j = 0; j < 4; ++j) {
            unsigned short hi = bf16_rn(xs[j]);
            hp[j] = hi;
            lp[j] = bf16_rn(xs[j] - bf16_to_f(hi));
        }
        int byte = row * 256 + ((k4 * 8) ^ ((row & 7) << 4));
        *reinterpret_cast<ushort4*>(reinterpret_cast<char*>(xhi) + byte) = h4;
        *reinterpret_cast<ushort4*>(reinterpret_cast<char*>(xlo) + byte) = l4;
    }
    __syncthreads();

    f32x4 acc[4][2];
    #pragma unroll
    for (int m = 0; m < 4; ++m)
        #pragma unroll
        for (int nt = 0; nt < 2; ++nt)
            acc[m][nt] = (f32x4){0.f, 0.f, 0.f, 0.f};

    #pragma unroll
    for (int kk = 0; kk < 4; ++kk) {
        #pragma unroll
        for (int m = 0; m < 4; ++m) {
            int row  = m * 16 + (lane & 15);
            int koff = kk * 64 + (lane >> 4) * 16;
            int byte = row * 256 + (koff ^ ((row & 7) << 4));
            bf16x8 ahi = *reinterpret_cast<const bf16x8*>(reinterpret_cast<char*>(xhi) + byte);
            bf16x8 alo = *reinterpret_cast<const bf16x8*>(reinterpret_cast<char*>(xlo) + byte);
            #pragma unroll
            for (int nt = 0; nt < 2; ++nt) {
                acc[m][nt] = __builtin_amdgcn_mfma_f32_16x16x32_bf16(ahi, bhi[nt][kk], acc[m][nt], 0, 0, 0);
                acc[m][nt] = __builtin_amdgcn_mfma_f32_16x16x32_bf16(ahi, blo[nt][kk], acc[m][nt], 0, 0, 0);
                acc[m][nt] = __builtin_amdgcn_mfma_f32_16x16x32_bf16(alo, bhi[nt][kk], acc[m][nt], 0, 0, 0);
            }
        }
    }

    // epilogue (fp16): D col = lane&15, row = (lane>>4)*4 + r
    #pragma unroll
    for (int m = 0; m < 4; ++m) {
        int row = rbase + m * 16 + (lane >> 4) * 4;
        int col = w * 32 + (lane & 15);
        #pragma unroll
        for (int nt = 0; nt < 2; ++nt) {
            #pragma unroll
            for (int r = 0; r < 4; ++r) {
                if (row + r < N)
                    Hh[(size_t)(row + r) * NODE_F + col + nt * 16] = __float2half(acc[m][nt][r]);
            }
        }
    }
}

// ---- gather: acc[d] = b + dinv[d]^2*H[d] + sum_{s in in(d)} dinv[s]dinv[d] H[s]
// fp16 H payload, fp32 accumulate; one wave per node, lane owns half2 (2 features).
__global__ __launch_bounds__(256) void gather_kernel(
    const __half* __restrict__ Hh, const int* __restrict__ csr_src,
    const int* __restrict__ row_start, const float* __restrict__ dinv,
    const float* __restrict__ b, float* __restrict__ acc, int N)
{
    int node = (blockIdx.x * blockDim.x + threadIdx.x) >> 6;
    int lane = threadIdx.x & 63;
    if (node >= N) return;

    const __half2* H2 = reinterpret_cast<const __half2*>(Hh);
    const float dd = dinv[node];
    float2 bb = reinterpret_cast<const float2*>(b)[lane];
    float2 h0 = __half22float2(H2[(size_t)node * 64 + lane]);
    float2 a;
    a.x = bb.x + dd * dd * h0.x;
    a.y = bb.y + dd * dd * h0.y;

    int i   = row_start[node];
    int end = row_start[node + 1];
    for (; i + 3 < end; i += 4) {
        int s0 = csr_src[i], s1 = csr_src[i + 1], s2 = csr_src[i + 2], s3 = csr_src[i + 3];
        float n0 = dinv[s0] * dd, n1 = dinv[s1] * dd;
        float n2 = dinv[s2] * dd, n3 = dinv[s3] * dd;
        float2 v0 = __half22float2(H2[(size_t)s0 * 64 + lane]);
        float2 v1 = __half22float2(H2[(size_t)s1 * 64 + lane]);
        float2 v2 = __half22float2(H2[(size_t)s2 * 64 + lane]);
        float2 v3 = __half22float2(H2[(size_t)s3 * 64 + lane]);
        a.x += v0.x * n0 + v1.x * n1 + v2.x * n2 + v3.x * n3;
        a.y += v0.y * n0 + v1.y * n1 + v2.y * n2 + v3.y * n3;
    }
    for (; i < end; ++i) {
        int s = csr_src[i];
        float nrm = dinv[s] * dd;
        float2 v = __half22float2(H2[(size_t)s * 64 + lane]);
        a.x += v.x * nrm;
        a.y += v.y * nrm;
    }
    reinterpret_cast<float2*>(acc)[(size_t)node * 64 + lane] = a;
}

// ---- FC head: out = tanh(relu(A) @ Wfc + bfc), one wave per row ---------

__global__ __launch_bounds__(256) void fc_kernel(const float* __restrict__ A,
                                                 const float* __restrict__ Wfc,
                                                 const float* __restrict__ bfc,
                                                 float* __restrict__ out, int N)
{
    int wid  = (blockIdx.x * blockDim.x + threadIdx.x) >> 6;
    int lane = threadIdx.x & 63;
    if (wid >= N) return;
    const float* row = A + (size_t)wid * NODE_F;
    float a0 = fmaxf(row[lane], 0.f);
    float a1 = fmaxf(row[lane + 64], 0.f);
    float p0 = a0 * Wfc[lane * 3 + 0] + a1 * Wfc[(lane + 64) * 3 + 0];
    float p1 = a0 * Wfc[lane * 3 + 1] + a1 * Wfc[(lane + 64) * 3 + 1];
    float p2 = a0 * Wfc[lane * 3 + 2] + a1 * Wfc[(lane + 64) * 3 + 2];
    #pragma unroll
    for (int off = 32; off > 0; off >>= 1) {
        p0 += __shfl_down(p0, off);
        p1 += __shfl_down(p1, off);
        p2 += __shfl_down(p2, off);
    }
    if (lane == 0) {
        out[(size_t)wid * 3 + 0] = tanhf(p0 + bfc[0]);
        out[(size_t)wid * 3 + 1] = tanhf(p1 + bfc[1]);
        out[(size_t)wid * 3 + 2] = tanhf(p2 + bfc[2]);
    }
}

extern "C" void kernel_launch(void* const* d_in, const int* in_sizes, int n_in,
                              void* d_out, int out_size, void* d_ws, size_t ws_size,
                              hipStream_t stream)
{
    const float* x    = (const float*)d_in[0];
    const int*   edge = (const int*)d_in[1];
    const float* W1   = (const float*)d_in[2];
    const float* b1   = (const float*)d_in[3];
    const float* W2   = (const float*)d_in[4];
    const float* b2   = (const float*)d_in[5];
    const float* Wfc  = (const float*)d_in[6];
    const float* bfc  = (const float*)d_in[7];
    float* out = (float*)d_out;

    const int N = in_sizes[0] / NODE_F;
    const int E = in_sizes[1] / 2;
    const int* src = edge;
    const int* dst = edge + E;

    char* ws = (char*)d_ws;
    size_t off = 0;
    auto alloc = [&](size_t bytes) {
        void* p = ws + off;
        off += (bytes + 511) & ~511ull;
        return p;
    };
    const int nblk1024 = (N + 1023) / 1024;
    float* dinv      = (float*)alloc((size_t)N * 4);
    int*   degE      = (int*)  alloc((size_t)N * 4);
    int*   cursor    = (int*)  alloc((size_t)N * 4);
    int*   row_start = (int*)  alloc((size_t)(N + 1) * 4);
    int*   bsum      = (int*)  alloc((size_t)nblk1024 * 4);
    int*   csr_src   = (int*)  alloc((size_t)E * 4);
    unsigned short* WhiT = (unsigned short*)alloc(2 * 128 * 128 * 2);
    unsigned short* WloT = (unsigned short*)alloc(2 * 128 * 128 * 2);
    __half* Hh       = (__half*)alloc((size_t)N * NODE_F * 2);
    float*  acc      = (float*) alloc((size_t)N * NODE_F * 4);
    (void)ws_size; (void)n_in; (void)out_size;

    const int B = 256;

    wconv_kernel<<<2, B, 0, stream>>>(W1, W2, WhiT, WloT);

    hipMemsetAsync(degE,   0, (size_t)N * 4, stream);
    hipMemsetAsync(cursor, 0, (size_t)N * 4, stream);
    deg_count_kernel<<<(E + B - 1) / B, B, 0, stream>>>(dst, degE, E);
    scan_block_kernel<<<nblk1024, B, 0, stream>>>(degE, row_start, bsum, N);
    scan_tops_kernel<<<1, 1024, 0, stream>>>(bsum, nblk1024);
    scan_finish_kernel<<<(N + B - 1) / B, B, 0, stream>>>(degE, row_start, bsum, dinv, N);
    fill_kernel<<<(E + B - 1) / B, B, 0, stream>>>(src, dst, row_start, cursor, csr_src, E);

    int gemm_grid   = (N + 63) / 64;
    int gather_grid = (N + 3) / 4;

    // layer 1
    gemm_mfma_kernel<false><<<gemm_grid, B, 0, stream>>>(x, WhiT, WloT, Hh, N);
    gather_kernel<<<gather_grid, B, 0, stream>>>(Hh, csr_src, row_start, dinv, b1, acc, N);

    // layer 2 (relu on load)
    gemm_mfma_kernel<true><<<gemm_grid, B, 0, stream>>>(acc, WhiT + 128 * 128, WloT + 128 * 128, Hh, N);
    gather_kernel<<<gather_grid, B, 0, stream>>>(Hh, csr_src, row_start, dinv, b2, acc, N);

    // FC head
    fc_kernel<<<(N + 3) / 4, B, 0, stream>>>(acc, Wfc, bfc, out, N);
}

// Round 5
// 368.791 us; speedup vs baseline: 15.1577x; 1.1630x over previous
//
#include <hip/hip_runtime.h>
#include <hip/hip_bf16.h>
#include <hip/hip_fp16.h>

// ResidualGNN: 2x GCNConv(128->128, relu) + FC(128->3, tanh), N=100000, E=1.6M, fp32.
// R4: single atomic pass (deg+rank), atomic-free fill fused into GEMM1 launch,
//     Hs = dinv[src]*H stored fp16 so gather is a pure row-sum.

#define NODE_F 128

typedef __attribute__((ext_vector_type(8))) short bf16x8;
typedef __attribute__((ext_vector_type(4))) float f32x4;

__device__ inline unsigned short bf16_rn(float x) {
    unsigned u = __builtin_bit_cast(unsigned, x);
    unsigned r = (u + 0x7fffu + ((u >> 16) & 1u)) >> 16;
    return (unsigned short)r;
}
__device__ inline float bf16_to_f(unsigned short h) {
    unsigned u = (unsigned)h << 16;
    return __builtin_bit_cast(float, u);
}

// ---- CSR build ----------------------------------------------------------

// one atomic pass: degree histogram AND per-edge rank (old value)
__global__ void deg_rank_kernel(const int* __restrict__ dst, int* __restrict__ degE,
                                int* __restrict__ rank, int E) {
    int i = blockIdx.x * blockDim.x + threadIdx.x;
    if (i < E) rank[i] = atomicAdd(&degE[dst[i]], 1);
}

__global__ __launch_bounds__(256) void scan_block_kernel(
    const int* __restrict__ degE, int* __restrict__ row_start,
    int* __restrict__ bsum, int N)
{
    __shared__ int s[256];
    const int tid = threadIdx.x;
    const int idx = blockIdx.x * 1024 + tid * 4;
    int v0 = (idx + 0 < N) ? degE[idx + 0] : 0;
    int v1 = (idx + 1 < N) ? degE[idx + 1] : 0;
    int v2 = (idx + 2 < N) ? degE[idx + 2] : 0;
    int v3 = (idx + 3 < N) ? degE[idx + 3] : 0;
    int t = v0 + v1 + v2 + v3;
    s[tid] = t;
    __syncthreads();
    #pragma unroll
    for (int off = 1; off < 256; off <<= 1) {
        int x = (tid >= off) ? s[tid - off] : 0;
        __syncthreads();
        s[tid] += x;
        __syncthreads();
    }
    int excl = s[tid] - t;
    if (idx + 0 < N) row_start[idx + 0] = excl;
    if (idx + 1 < N) row_start[idx + 1] = excl + v0;
    if (idx + 2 < N) row_start[idx + 2] = excl + v0 + v1;
    if (idx + 3 < N) row_start[idx + 3] = excl + v0 + v1 + v2;
    if (tid == 255) bsum[blockIdx.x] = s[255];
}

__global__ __launch_bounds__(1024) void scan_tops_kernel(int* __restrict__ bsum, int nb) {
    __shared__ int s[1024];
    const int tid = threadIdx.x;
    int v = (tid < nb) ? bsum[tid] : 0;
    s[tid] = v;
    __syncthreads();
    #pragma unroll
    for (int off = 1; off < 1024; off <<= 1) {
        int x = (tid >= off) ? s[tid - off] : 0;
        __syncthreads();
        s[tid] += x;
        __syncthreads();
    }
    if (tid < nb) bsum[tid] = s[tid] - v;
}

__global__ void scan_finish_kernel(const int* __restrict__ degE, int* __restrict__ row_start,
                                   const int* __restrict__ bsum, float* __restrict__ dinv, int N)
{
    int i = blockIdx.x * blockDim.x + threadIdx.x;
    if (i >= N) return;
    int rs = row_start[i] + bsum[i >> 10];
    row_start[i] = rs;
    dinv[i] = rsqrtf((float)degE[i] + 1.0f);
    if (i == N - 1) row_start[N] = rs + degE[i];
}

// ---- W -> bf16 hi/lo, transposed to [n][k]; both weights in one launch --

__global__ __launch_bounds__(256) void wconv_kernel(const float* __restrict__ W1,
                                                    const float* __restrict__ W2,
                                                    unsigned short* __restrict__ WhiT,
                                                    unsigned short* __restrict__ WloT)
{
    const float* W = blockIdx.x ? W2 : W1;
    unsigned short* hiT = WhiT + blockIdx.x * 128 * 128;
    unsigned short* loT = WloT + blockIdx.x * 128 * 128;
    int tid = threadIdx.x;
    for (int i = tid; i < 128 * 128; i += 256) {
        int k = i >> 7, n = i & 127;
        float x = W[i];
        unsigned short hi = bf16_rn(x);
        float lo = x - bf16_to_f(hi);
        hiT[n * 128 + k] = hi;
        loT[n * 128 + k] = bf16_rn(lo);
    }
}

// ---- GEMM body: Hs[rows,128](fp16) = dinv[row] * ((relu?)X @ W) ---------
// block computes 64 rows x 128 cols with 4 waves; wave w owns cols w*32..+31.

template<bool RELU_IN>
__device__ __forceinline__ void gemm_body(
    const float* __restrict__ X, const unsigned short* __restrict__ WhiT,
    const unsigned short* __restrict__ WloT, const float* __restrict__ dinv,
    __half* __restrict__ Hs, int N, int bid,
    unsigned short* xhi, unsigned short* xlo)
{
    const int tid  = threadIdx.x;
    const int lane = tid & 63;
    const int w    = tid >> 6;
    const int rbase = bid * 64;

    bf16x8 bhi[2][4], blo[2][4];
    {
        int n0   = w * 32 + (lane & 15);
        int koct = (lane >> 4) * 8;
        #pragma unroll
        for (int nt = 0; nt < 2; ++nt) {
            #pragma unroll
            for (int kk = 0; kk < 4; ++kk) {
                size_t o = (size_t)(n0 + nt * 16) * 128 + kk * 32 + koct;
                bhi[nt][kk] = *reinterpret_cast<const bf16x8*>(WhiT + o);
                blo[nt][kk] = *reinterpret_cast<const bf16x8*>(WloT + o);
            }
        }
    }

    #pragma unroll
    for (int it = 0; it < 8; ++it) {
        int f   = it * 256 + tid;
        int row = f >> 5;
        int k4  = f & 31;
        float4 v = make_float4(0.f, 0.f, 0.f, 0.f);
        if (rbase + row < N)
            v = *reinterpret_cast<const float4*>(X + (size_t)(rbase + row) * NODE_F + k4 * 4);
        if (RELU_IN) {
            v.x = fmaxf(v.x, 0.f); v.y = fmaxf(v.y, 0.f);
            v.z = fmaxf(v.z, 0.f); v.w = fmaxf(v.w, 0.f);
        }
        float xs[4] = {v.x, v.y, v.z, v.w};
        ushort4 h4, l4;
        unsigned short* hp = &h4.x;
        unsigned short* lp = &l4.x;
        #pragma unroll
        for (int j = 0; j < 4; ++j) {
            unsigned short hi = bf16_rn(xs[j]);
            hp[j] = hi;
            lp[j] = bf16_rn(xs[j] - bf16_to_f(hi));
        }
        int byte = row * 256 + ((k4 * 8) ^ ((row & 7) << 4));
        *reinterpret_cast<ushort4*>(reinterpret_cast<char*>(xhi) + byte) = h4;
        *reinterpret_cast<ushort4*>(reinterpret_cast<char*>(xlo) + byte) = l4;
    }
    __syncthreads();

    f32x4 acc[4][2];
    #pragma unroll
    for (int m = 0; m < 4; ++m)
        #pragma unroll
        for (int nt = 0; nt < 2; ++nt)
            acc[m][nt] = (f32x4){0.f, 0.f, 0.f, 0.f};

    #pragma unroll
    for (int kk = 0; kk < 4; ++kk) {
        #pragma unroll
        for (int m = 0; m < 4; ++m) {
            int row  = m * 16 + (lane & 15);
            int koff = kk * 64 + (lane >> 4) * 16;
            int byte = row * 256 + (koff ^ ((row & 7) << 4));
            bf16x8 ahi = *reinterpret_cast<const bf16x8*>(reinterpret_cast<char*>(xhi) + byte);
            bf16x8 alo = *reinterpret_cast<const bf16x8*>(reinterpret_cast<char*>(xlo) + byte);
            #pragma unroll
            for (int nt = 0; nt < 2; ++nt) {
                acc[m][nt] = __builtin_amdgcn_mfma_f32_16x16x32_bf16(ahi, bhi[nt][kk], acc[m][nt], 0, 0, 0);
                acc[m][nt] = __builtin_amdgcn_mfma_f32_16x16x32_bf16(ahi, blo[nt][kk], acc[m][nt], 0, 0, 0);
                acc[m][nt] = __builtin_amdgcn_mfma_f32_16x16x32_bf16(alo, bhi[nt][kk], acc[m][nt], 0, 0, 0);
            }
        }
    }

    // epilogue (fp16, pre-scaled by dinv): D col = lane&15, row = (lane>>4)*4 + r
    #pragma unroll
    for (int m = 0; m < 4; ++m) {
        int row = rbase + m * 16 + (lane >> 4) * 4;
        int col = w * 32 + (lane & 15);
        #pragma unroll
        for (int nt = 0; nt < 2; ++nt) {
            #pragma unroll
            for (int r = 0; r < 4; ++r) {
                if (row + r < N)
                    Hs[(size_t)(row + r) * NODE_F + col + nt * 16] =
                        __float2half(acc[m][nt][r] * dinv[row + r]);
            }
        }
    }
}

// GEMM1 + atomic-free CSR fill fused in one launch (independent work).
__global__ __launch_bounds__(256) void gemm1_fill_kernel(
    const float* __restrict__ X, const unsigned short* __restrict__ WhiT,
    const unsigned short* __restrict__ WloT, const float* __restrict__ dinv,
    __half* __restrict__ Hs, int N, int gemm_blocks,
    const int* __restrict__ src, const int* __restrict__ dst,
    const int* __restrict__ rank, const int* __restrict__ row_start,
    int* __restrict__ csr_src, int E)
{
    __shared__ unsigned short xhi[64 * 128];
    __shared__ unsigned short xlo[64 * 128];
    if (blockIdx.x < (unsigned)gemm_blocks) {
        gemm_body<false>(X, WhiT, WloT, dinv, Hs, N, blockIdx.x, xhi, xlo);
    } else {
        int e = (blockIdx.x - gemm_blocks) * 256 + threadIdx.x;
        if (e < E)
            csr_src[row_start[dst[e]] + rank[e]] = src[e];
    }
}

template<bool RELU_IN>
__global__ __launch_bounds__(256) void gemm_mfma_kernel(
    const float* __restrict__ X, const unsigned short* __restrict__ WhiT,
    const unsigned short* __restrict__ WloT, const float* __restrict__ dinv,
    __half* __restrict__ Hs, int N)
{
    __shared__ unsigned short xhi[64 * 128];
    __shared__ unsigned short xlo[64 * 128];
    gemm_body<RELU_IN>(X, WhiT, WloT, dinv, Hs, N, blockIdx.x, xhi, xlo);
}

// ---- gather: acc[d] = b + dinv[d] * (Hs[d] + sum_{s in in(d)} Hs[s]) ----
__global__ __launch_bounds__(256) void gather_kernel(
    const __half* __restrict__ Hs, const int* __restrict__ csr_src,
    const int* __restrict__ row_start, const float* __restrict__ dinv,
    const float* __restrict__ b, float* __restrict__ acc, int N)
{
    int node = (blockIdx.x * blockDim.x + threadIdx.x) >> 6;
    int lane = threadIdx.x & 63;
    if (node >= N) return;

    const __half2* H2 = reinterpret_cast<const __half2*>(Hs);
    float2 a = __half22float2(H2[(size_t)node * 64 + lane]);   // self-loop term

    int i   = row_start[node];
    int end = row_start[node + 1];
    for (; i + 3 < end; i += 4) {
        int s0 = csr_src[i], s1 = csr_src[i + 1], s2 = csr_src[i + 2], s3 = csr_src[i + 3];
        float2 v0 = __half22float2(H2[(size_t)s0 * 64 + lane]);
        float2 v1 = __half22float2(H2[(size_t)s1 * 64 + lane]);
        float2 v2 = __half22float2(H2[(size_t)s2 * 64 + lane]);
        float2 v3 = __half22float2(H2[(size_t)s3 * 64 + lane]);
        a.x += (v0.x + v1.x) + (v2.x + v3.x);
        a.y += (v0.y + v1.y) + (v2.y + v3.y);
    }
    for (; i < end; ++i) {
        int s = csr_src[i];
        float2 v = __half22float2(H2[(size_t)s * 64 + lane]);
        a.x += v.x;
        a.y += v.y;
    }

    const float dd = dinv[node];
    float2 bb = reinterpret_cast<const float2*>(b)[lane];
    float2 o;
    o.x = bb.x + dd * a.x;
    o.y = bb.y + dd * a.y;
    reinterpret_cast<float2*>(acc)[(size_t)node * 64 + lane] = o;
}

// ---- FC head: out = tanh(relu(A) @ Wfc + bfc), one wave per row ---------

__global__ __launch_bounds__(256) void fc_kernel(const float* __restrict__ A,
                                                 const float* __restrict__ Wfc,
                                                 const float* __restrict__ bfc,
                                                 float* __restrict__ out, int N)
{
    int wid  = (blockIdx.x * blockDim.x + threadIdx.x) >> 6;
    int lane = threadIdx.x & 63;
    if (wid >= N) return;
    const float* row = A + (size_t)wid * NODE_F;
    float a0 = fmaxf(row[lane], 0.f);
    float a1 = fmaxf(row[lane + 64], 0.f);
    float p0 = a0 * Wfc[lane * 3 + 0] + a1 * Wfc[(lane + 64) * 3 + 0];
    float p1 = a0 * Wfc[lane * 3 + 1] + a1 * Wfc[(lane + 64) * 3 + 1];
    float p2 = a0 * Wfc[lane * 3 + 2] + a1 * Wfc[(lane + 64) * 3 + 2];
    #pragma unroll
    for (int off = 32; off > 0; off >>= 1) {
        p0 += __shfl_down(p0, off);
        p1 += __shfl_down(p1, off);
        p2 += __shfl_down(p2, off);
    }
    if (lane == 0) {
        out[(size_t)wid * 3 + 0] = tanhf(p0 + bfc[0]);
        out[(size_t)wid * 3 + 1] = tanhf(p1 + bfc[1]);
        out[(size_t)wid * 3 + 2] = tanhf(p2 + bfc[2]);
    }
}

extern "C" void kernel_launch(void* const* d_in, const int* in_sizes, int n_in,
                              void* d_out, int out_size, void* d_ws, size_t ws_size,
                              hipStream_t stream)
{
    const float* x    = (const float*)d_in[0];
    const int*   edge = (const int*)d_in[1];
    const float* W1   = (const float*)d_in[2];
    const float* b1   = (const float*)d_in[3];
    const float* W2   = (const float*)d_in[4];
    const float* b2   = (const float*)d_in[5];
    const float* Wfc  = (const float*)d_in[6];
    const float* bfc  = (const float*)d_in[7];
    float* out = (float*)d_out;

    const int N = in_sizes[0] / NODE_F;
    const int E = in_sizes[1] / 2;
    const int* src = edge;
    const int* dst = edge + E;

    char* ws = (char*)d_ws;
    size_t off = 0;
    auto alloc = [&](size_t bytes) {
        void* p = ws + off;
        off += (bytes + 511) & ~511ull;
        return p;
    };
    const int nblk1024 = (N + 1023) / 1024;
    float* dinv      = (float*)alloc((size_t)N * 4);
    int*   degE      = (int*)  alloc((size_t)N * 4);
    int*   rank      = (int*)  alloc((size_t)E * 4);
    int*   row_start = (int*)  alloc((size_t)(N + 1) * 4);
    int*   bsum      = (int*)  alloc((size_t)nblk1024 * 4);
    int*   csr_src   = (int*)  alloc((size_t)E * 4);
    unsigned short* WhiT = (unsigned short*)alloc(2 * 128 * 128 * 2);
    unsigned short* WloT = (unsigned short*)alloc(2 * 128 * 128 * 2);
    __half* Hs       = (__half*)alloc((size_t)N * NODE_F * 2);
    float*  acc      = (float*) alloc((size_t)N * NODE_F * 4);
    (void)ws_size; (void)n_in; (void)out_size;

    const int B = 256;

    wconv_kernel<<<2, B, 0, stream>>>(W1, W2, WhiT, WloT);

    hipMemsetAsync(degE, 0, (size_t)N * 4, stream);
    deg_rank_kernel<<<(E + B - 1) / B, B, 0, stream>>>(dst, degE, rank, E);
    scan_block_kernel<<<nblk1024, B, 0, stream>>>(degE, row_start, bsum, N);
    scan_tops_kernel<<<1, 1024, 0, stream>>>(bsum, nblk1024);
    scan_finish_kernel<<<(N + B - 1) / B, B, 0, stream>>>(degE, row_start, bsum, dinv, N);

    int gemm_grid   = (N + 63) / 64;
    int fill_grid   = (E + B - 1) / B;
    int gather_grid = (N + 3) / 4;

    // layer 1 GEMM fused with CSR fill (independent work, one launch)
    gemm1_fill_kernel<<<gemm_grid + fill_grid, B, 0, stream>>>(
        x, WhiT, WloT, dinv, Hs, N, gemm_grid,
        src, dst, rank, row_start, csr_src, E);
    gather_kernel<<<gather_grid, B, 0, stream>>>(Hs, csr_src, row_start, dinv, b1, acc, N);

    // layer 2 (relu on load)
    gemm_mfma_kernel<true><<<gemm_grid, B, 0, stream>>>(acc, WhiT + 128 * 128, WloT + 128 * 128,
                                                        dinv, Hs, N);
    gather_kernel<<<gather_grid, B, 0, stream>>>(Hs, csr_src, row_start, dinv, b2, acc, N);

    // FC head
    fc_kernel<<<(N + 3) / 4, B, 0, stream>>>(acc, Wfc, bfc, out, N);
}

// Round 6
// 351.966 us; speedup vs baseline: 15.8823x; 1.0478x over previous
//
#include <hip/hip_runtime.h>
#include <hip/hip_bf16.h>
#include <hip/hip_fp16.h>

// ResidualGNN: 2x GCNConv(128->128, relu) + FC(128->3, tanh), N=100000, E=1.6M, fp32.
// R5: hybridA = [deg_rank || gemm1(unscaled)], hybridB = [fill || scale-H-by-dinv],
//     gather1 emits relu'd split-bf16 (feeds gemm2 staging directly),
//     gather2 + FC head fused (no acc round-trip), gather unroll x8.

#define NODE_F 128

typedef __attribute__((ext_vector_type(8))) short bf16x8;
typedef __attribute__((ext_vector_type(8))) unsigned short u16x8;
typedef __attribute__((ext_vector_type(4))) float f32x4;

__device__ inline unsigned short bf16_rn(float x) {
    unsigned u = __builtin_bit_cast(unsigned, x);
    unsigned r = (u + 0x7fffu + ((u >> 16) & 1u)) >> 16;
    return (unsigned short)r;
}
__device__ inline float bf16_to_f(unsigned short h) {
    unsigned u = (unsigned)h << 16;
    return __builtin_bit_cast(float, u);
}

// ---- W -> bf16 hi/lo, transposed to [n][k]; both weights in one launch --

__global__ __launch_bounds__(256) void wconv_kernel(const float* __restrict__ W1,
                                                    const float* __restrict__ W2,
                                                    unsigned short* __restrict__ WhiT,
                                                    unsigned short* __restrict__ WloT)
{
    const float* W = blockIdx.x ? W2 : W1;
    unsigned short* hiT = WhiT + blockIdx.x * 128 * 128;
    unsigned short* loT = WloT + blockIdx.x * 128 * 128;
    int tid = threadIdx.x;
    for (int i = tid; i < 128 * 128; i += 256) {
        int k = i >> 7, n = i & 127;
        float x = W[i];
        unsigned short hi = bf16_rn(x);
        float lo = x - bf16_to_f(hi);
        hiT[n * 128 + k] = hi;
        loT[n * 128 + k] = bf16_rn(lo);
    }
}

// ---- scan ---------------------------------------------------------------

__global__ __launch_bounds__(256) void scan_block_kernel(
    const int* __restrict__ degE, int* __restrict__ row_start,
    int* __restrict__ bsum, int N)
{
    __shared__ int s[256];
    const int tid = threadIdx.x;
    const int idx = blockIdx.x * 1024 + tid * 4;
    int v0 = (idx + 0 < N) ? degE[idx + 0] : 0;
    int v1 = (idx + 1 < N) ? degE[idx + 1] : 0;
    int v2 = (idx + 2 < N) ? degE[idx + 2] : 0;
    int v3 = (idx + 3 < N) ? degE[idx + 3] : 0;
    int t = v0 + v1 + v2 + v3;
    s[tid] = t;
    __syncthreads();
    #pragma unroll
    for (int off = 1; off < 256; off <<= 1) {
        int x = (tid >= off) ? s[tid - off] : 0;
        __syncthreads();
        s[tid] += x;
        __syncthreads();
    }
    int excl = s[tid] - t;
    if (idx + 0 < N) row_start[idx + 0] = excl;
    if (idx + 1 < N) row_start[idx + 1] = excl + v0;
    if (idx + 2 < N) row_start[idx + 2] = excl + v0 + v1;
    if (idx + 3 < N) row_start[idx + 3] = excl + v0 + v1 + v2;
    if (tid == 255) bsum[blockIdx.x] = s[255];
}

__global__ __launch_bounds__(1024) void scan_tops_kernel(int* __restrict__ bsum, int nb) {
    __shared__ int s[1024];
    const int tid = threadIdx.x;
    int v = (tid < nb) ? bsum[tid] : 0;
    s[tid] = v;
    __syncthreads();
    #pragma unroll
    for (int off = 1; off < 1024; off <<= 1) {
        int x = (tid >= off) ? s[tid - off] : 0;
        __syncthreads();
        s[tid] += x;
        __syncthreads();
    }
    if (tid < nb) bsum[tid] = s[tid] - v;
}

__global__ void scan_finish_kernel(const int* __restrict__ degE, int* __restrict__ row_start,
                                   const int* __restrict__ bsum, float* __restrict__ dinv, int N)
{
    int i = blockIdx.x * blockDim.x + threadIdx.x;
    if (i >= N) return;
    int rs = row_start[i] + bsum[i >> 10];
    row_start[i] = rs;
    dinv[i] = rsqrtf((float)degE[i] + 1.0f);
    if (i == N - 1) row_start[N] = rs + degE[i];
}

// ---- GEMM body ----------------------------------------------------------
// block computes 64 rows x 128 cols with 4 waves; wave w owns cols w*32..+31.
// SPLIT_IN: input is pre-split ushort hi/lo arrays (copy staging);
// else fp32 input (convert staging). SCALE_OUT: multiply rows by dinv.

template<bool SPLIT_IN, bool SCALE_OUT>
__device__ __forceinline__ void gemm_body(
    const float* __restrict__ Xf,
    const unsigned short* __restrict__ Xhi_g, const unsigned short* __restrict__ Xlo_g,
    const unsigned short* __restrict__ WhiT, const unsigned short* __restrict__ WloT,
    const float* __restrict__ dinv,
    __half* __restrict__ Hout, int N, int bid,
    unsigned short* xhi, unsigned short* xlo)
{
    const int tid  = threadIdx.x;
    const int lane = tid & 63;
    const int w    = tid >> 6;
    const int rbase = bid * 64;

    bf16x8 bhi[2][4], blo[2][4];
    {
        int n0   = w * 32 + (lane & 15);
        int koct = (lane >> 4) * 8;
        #pragma unroll
        for (int nt = 0; nt < 2; ++nt) {
            #pragma unroll
            for (int kk = 0; kk < 4; ++kk) {
                size_t o = (size_t)(n0 + nt * 16) * 128 + kk * 32 + koct;
                bhi[nt][kk] = *reinterpret_cast<const bf16x8*>(WhiT + o);
                blo[nt][kk] = *reinterpret_cast<const bf16x8*>(WloT + o);
            }
        }
    }

    if (!SPLIT_IN) {
        #pragma unroll
        for (int it = 0; it < 8; ++it) {
            int f   = it * 256 + tid;
            int row = f >> 5;
            int k4  = f & 31;
            float4 v = make_float4(0.f, 0.f, 0.f, 0.f);
            if (rbase + row < N)
                v = *reinterpret_cast<const float4*>(Xf + (size_t)(rbase + row) * NODE_F + k4 * 4);
            float xs[4] = {v.x, v.y, v.z, v.w};
            ushort4 h4, l4;
            unsigned short* hp = &h4.x;
            unsigned short* lp = &l4.x;
            #pragma unroll
            for (int j = 0; j < 4; ++j) {
                unsigned short hi = bf16_rn(xs[j]);
                hp[j] = hi;
                lp[j] = bf16_rn(xs[j] - bf16_to_f(hi));
            }
            int byte = row * 256 + ((k4 * 8) ^ ((row & 7) << 4));
            *reinterpret_cast<ushort4*>(reinterpret_cast<char*>(xhi) + byte) = h4;
            *reinterpret_cast<ushort4*>(reinterpret_cast<char*>(xlo) + byte) = l4;
        }
    } else {
        #pragma unroll
        for (int it = 0; it < 4; ++it) {
            int idx = it * 256 + tid;           // u16x8 units; 1024 per array
            int row = idx >> 4;
            int k8  = idx & 15;
            u16x8 h = {0, 0, 0, 0, 0, 0, 0, 0};
            u16x8 l = {0, 0, 0, 0, 0, 0, 0, 0};
            if (rbase + row < N) {
                size_t g = (size_t)(rbase + row) * NODE_F + k8 * 8;
                h = *reinterpret_cast<const u16x8*>(Xhi_g + g);
                l = *reinterpret_cast<const u16x8*>(Xlo_g + g);
            }
            int byte = row * 256 + ((k8 * 16) ^ ((row & 7) << 4));
            *reinterpret_cast<u16x8*>(reinterpret_cast<char*>(xhi) + byte) = h;
            *reinterpret_cast<u16x8*>(reinterpret_cast<char*>(xlo) + byte) = l;
        }
    }
    __syncthreads();

    f32x4 acc[4][2];
    #pragma unroll
    for (int m = 0; m < 4; ++m)
        #pragma unroll
        for (int nt = 0; nt < 2; ++nt)
            acc[m][nt] = (f32x4){0.f, 0.f, 0.f, 0.f};

    #pragma unroll
    for (int kk = 0; kk < 4; ++kk) {
        #pragma unroll
        for (int m = 0; m < 4; ++m) {
            int row  = m * 16 + (lane & 15);
            int koff = kk * 64 + (lane >> 4) * 16;
            int byte = row * 256 + (koff ^ ((row & 7) << 4));
            bf16x8 ahi = *reinterpret_cast<const bf16x8*>(reinterpret_cast<char*>(xhi) + byte);
            bf16x8 alo = *reinterpret_cast<const bf16x8*>(reinterpret_cast<char*>(xlo) + byte);
            #pragma unroll
            for (int nt = 0; nt < 2; ++nt) {
                acc[m][nt] = __builtin_amdgcn_mfma_f32_16x16x32_bf16(ahi, bhi[nt][kk], acc[m][nt], 0, 0, 0);
                acc[m][nt] = __builtin_amdgcn_mfma_f32_16x16x32_bf16(ahi, blo[nt][kk], acc[m][nt], 0, 0, 0);
                acc[m][nt] = __builtin_amdgcn_mfma_f32_16x16x32_bf16(alo, bhi[nt][kk], acc[m][nt], 0, 0, 0);
            }
        }
    }

    // epilogue: D col = lane&15, row = (lane>>4)*4 + r
    #pragma unroll
    for (int m = 0; m < 4; ++m) {
        int row = rbase + m * 16 + (lane >> 4) * 4;
        int col = w * 32 + (lane & 15);
        #pragma unroll
        for (int nt = 0; nt < 2; ++nt) {
            #pragma unroll
            for (int r = 0; r < 4; ++r) {
                if (row + r < N) {
                    float v = acc[m][nt][r];
                    if (SCALE_OUT) v *= dinv[row + r];
                    Hout[(size_t)(row + r) * NODE_F + col + nt * 16] = __float2half(v);
                }
            }
        }
    }
}

// ---- hybridA: [deg_rank || gemm1(unscaled)] -----------------------------

__global__ __launch_bounds__(256) void hybridA_kernel(
    const int* __restrict__ dst, int* __restrict__ degE, int* __restrict__ rank,
    int E, int deg_blocks,
    const float* __restrict__ X, const unsigned short* __restrict__ WhiT,
    const unsigned short* __restrict__ WloT, __half* __restrict__ H, int N)
{
    __shared__ unsigned short xhi[64 * 128];
    __shared__ unsigned short xlo[64 * 128];
    if ((int)blockIdx.x < deg_blocks) {
        int e = blockIdx.x * 256 + threadIdx.x;
        if (e < E) rank[e] = atomicAdd(&degE[dst[e]], 1);
    } else {
        gemm_body<false, false>(X, nullptr, nullptr, WhiT, WloT, nullptr,
                                H, N, blockIdx.x - deg_blocks, xhi, xlo);
    }
}

// ---- hybridB: [fill || scale H by dinv (from degE)] ---------------------

__global__ __launch_bounds__(256) void hybridB_kernel(
    const int* __restrict__ src, const int* __restrict__ dst,
    const int* __restrict__ rank, const int* __restrict__ row_start,
    int* __restrict__ csr_src, int E, int fill_blocks,
    __half* __restrict__ H, const int* __restrict__ degE, int N)
{
    if ((int)blockIdx.x < fill_blocks) {
        int e = blockIdx.x * 256 + threadIdx.x;
        if (e < E) csr_src[row_start[dst[e]] + rank[e]] = src[e];
    } else {
        int idx = (blockIdx.x - fill_blocks) * 256 + threadIdx.x;  // 8-half units
        if (idx < N * 16) {
            int row = idx >> 4;
            float ds = rsqrtf((float)degE[row] + 1.0f);
            __half2* p = reinterpret_cast<__half2*>(H) + (size_t)idx * 4;
            #pragma unroll
            for (int j = 0; j < 4; ++j) {
                float2 v = __half22float2(p[j]);
                v.x *= ds; v.y *= ds;
                p[j] = __float22half2_rn(v);
            }
        }
    }
}

// ---- gather1: o = relu(b + dinv[d]*(Hs[d] + sum Hs[s])) -> split bf16 ---

__global__ __launch_bounds__(256) void gather1_kernel(
    const __half* __restrict__ Hs, const int* __restrict__ csr_src,
    const int* __restrict__ row_start, const float* __restrict__ dinv,
    const float* __restrict__ b,
    unsigned short* __restrict__ Xhi, unsigned short* __restrict__ Xlo, int N)
{
    int node = (blockIdx.x * blockDim.x + threadIdx.x) >> 6;
    int lane = threadIdx.x & 63;
    if (node >= N) return;

    const __half2* H2 = reinterpret_cast<const __half2*>(Hs);
    float2 a = __half22float2(H2[(size_t)node * 64 + lane]);

    int i   = row_start[node];
    int end = row_start[node + 1];
    for (; i + 7 < end; i += 8) {
        int s0 = csr_src[i + 0], s1 = csr_src[i + 1], s2 = csr_src[i + 2], s3 = csr_src[i + 3];
        int s4 = csr_src[i + 4], s5 = csr_src[i + 5], s6 = csr_src[i + 6], s7 = csr_src[i + 7];
        float2 v0 = __half22float2(H2[(size_t)s0 * 64 + lane]);
        float2 v1 = __half22float2(H2[(size_t)s1 * 64 + lane]);
        float2 v2 = __half22float2(H2[(size_t)s2 * 64 + lane]);
        float2 v3 = __half22float2(H2[(size_t)s3 * 64 + lane]);
        float2 v4 = __half22float2(H2[(size_t)s4 * 64 + lane]);
        float2 v5 = __half22float2(H2[(size_t)s5 * 64 + lane]);
        float2 v6 = __half22float2(H2[(size_t)s6 * 64 + lane]);
        float2 v7 = __half22float2(H2[(size_t)s7 * 64 + lane]);
        a.x += ((v0.x + v1.x) + (v2.x + v3.x)) + ((v4.x + v5.x) + (v6.x + v7.x));
        a.y += ((v0.y + v1.y) + (v2.y + v3.y)) + ((v4.y + v5.y) + (v6.y + v7.y));
    }
    for (; i < end; ++i) {
        int s = csr_src[i];
        float2 v = __half22float2(H2[(size_t)s * 64 + lane]);
        a.x += v.x;
        a.y += v.y;
    }

    const float dd = dinv[node];
    float2 bb = reinterpret_cast<const float2*>(b)[lane];
    float rx = fmaxf(bb.x + dd * a.x, 0.f);
    float ry = fmaxf(bb.y + dd * a.y, 0.f);
    unsigned short hx = bf16_rn(rx), hy = bf16_rn(ry);
    unsigned short lx = bf16_rn(rx - bf16_to_f(hx));
    unsigned short ly = bf16_rn(ry - bf16_to_f(hy));
    reinterpret_cast<ushort2*>(Xhi)[(size_t)node * 64 + lane] = make_ushort2(hx, hy);
    reinterpret_cast<ushort2*>(Xlo)[(size_t)node * 64 + lane] = make_ushort2(lx, ly);
}

// ---- gather2 + FC: out = tanh(relu(b + dd*(sum)) @ Wfc + bfc) -----------

__global__ __launch_bounds__(256) void gather2fc_kernel(
    const __half* __restrict__ Hs, const int* __restrict__ csr_src,
    const int* __restrict__ row_start, const float* __restrict__ dinv,
    const float* __restrict__ b, const float* __restrict__ Wfc,
    const float* __restrict__ bfc, float* __restrict__ out, int N)
{
    int node = (blockIdx.x * blockDim.x + threadIdx.x) >> 6;
    int lane = threadIdx.x & 63;
    if (node >= N) return;

    const __half2* H2 = reinterpret_cast<const __half2*>(Hs);
    float2 a = __half22float2(H2[(size_t)node * 64 + lane]);

    int i   = row_start[node];
    int end = row_start[node + 1];
    for (; i + 7 < end; i += 8) {
        int s0 = csr_src[i + 0], s1 = csr_src[i + 1], s2 = csr_src[i + 2], s3 = csr_src[i + 3];
        int s4 = csr_src[i + 4], s5 = csr_src[i + 5], s6 = csr_src[i + 6], s7 = csr_src[i + 7];
        float2 v0 = __half22float2(H2[(size_t)s0 * 64 + lane]);
        float2 v1 = __half22float2(H2[(size_t)s1 * 64 + lane]);
        float2 v2 = __half22float2(H2[(size_t)s2 * 64 + lane]);
        float2 v3 = __half22float2(H2[(size_t)s3 * 64 + lane]);
        float2 v4 = __half22float2(H2[(size_t)s4 * 64 + lane]);
        float2 v5 = __half22float2(H2[(size_t)s5 * 64 + lane]);
        float2 v6 = __half22float2(H2[(size_t)s6 * 64 + lane]);
        float2 v7 = __half22float2(H2[(size_t)s7 * 64 + lane]);
        a.x += ((v0.x + v1.x) + (v2.x + v3.x)) + ((v4.x + v5.x) + (v6.x + v7.x));
        a.y += ((v0.y + v1.y) + (v2.y + v3.y)) + ((v4.y + v5.y) + (v6.y + v7.y));
    }
    for (; i < end; ++i) {
        int s = csr_src[i];
        float2 v = __half22float2(H2[(size_t)s * 64 + lane]);
        a.x += v.x;
        a.y += v.y;
    }

    const float dd = dinv[node];
    float2 bb = reinterpret_cast<const float2*>(b)[lane];
    float rx = fmaxf(bb.x + dd * a.x, 0.f);
    float ry = fmaxf(bb.y + dd * a.y, 0.f);

    // FC: lane holds features 2*lane, 2*lane+1
    const float* w0 = Wfc + (size_t)(2 * lane) * 3;
    float p0 = rx * w0[0] + ry * w0[3];
    float p1 = rx * w0[1] + ry * w0[4];
    float p2 = rx * w0[2] + ry * w0[5];
    #pragma unroll
    for (int off = 32; off > 0; off >>= 1) {
        p0 += __shfl_down(p0, off);
        p1 += __shfl_down(p1, off);
        p2 += __shfl_down(p2, off);
    }
    if (lane == 0) {
        out[(size_t)node * 3 + 0] = tanhf(p0 + bfc[0]);
        out[(size_t)node * 3 + 1] = tanhf(p1 + bfc[1]);
        out[(size_t)node * 3 + 2] = tanhf(p2 + bfc[2]);
    }
}

// ---- gemm2 --------------------------------------------------------------

__global__ __launch_bounds__(256) void gemm2_kernel(
    const unsigned short* __restrict__ Xhi_g, const unsigned short* __restrict__ Xlo_g,
    const unsigned short* __restrict__ WhiT, const unsigned short* __restrict__ WloT,
    const float* __restrict__ dinv, __half* __restrict__ Hs, int N)
{
    __shared__ unsigned short xhi[64 * 128];
    __shared__ unsigned short xlo[64 * 128];
    gemm_body<true, true>(nullptr, Xhi_g, Xlo_g, WhiT, WloT, dinv,
                          Hs, N, blockIdx.x, xhi, xlo);
}

extern "C" void kernel_launch(void* const* d_in, const int* in_sizes, int n_in,
                              void* d_out, int out_size, void* d_ws, size_t ws_size,
                              hipStream_t stream)
{
    const float* x    = (const float*)d_in[0];
    const int*   edge = (const int*)d_in[1];
    const float* W1   = (const float*)d_in[2];
    const float* b1   = (const float*)d_in[3];
    const float* W2   = (const float*)d_in[4];
    const float* b2   = (const float*)d_in[5];
    const float* Wfc  = (const float*)d_in[6];
    const float* bfc  = (const float*)d_in[7];
    float* out = (float*)d_out;

    const int N = in_sizes[0] / NODE_F;
    const int E = in_sizes[1] / 2;
    const int* src = edge;
    const int* dst = edge + E;

    char* ws = (char*)d_ws;
    size_t off = 0;
    auto alloc = [&](size_t bytes) {
        void* p = ws + off;
        off += (bytes + 511) & ~511ull;
        return p;
    };
    const int nblk1024 = (N + 1023) / 1024;
    float* dinv      = (float*)alloc((size_t)N * 4);
    int*   degE      = (int*)  alloc((size_t)N * 4);
    int*   rank      = (int*)  alloc((size_t)E * 4);
    int*   row_start = (int*)  alloc((size_t)(N + 1) * 4);
    int*   bsum      = (int*)  alloc((size_t)nblk1024 * 4);
    int*   csr_src   = (int*)  alloc((size_t)E * 4);
    unsigned short* WhiT = (unsigned short*)alloc(2 * 128 * 128 * 2);
    unsigned short* WloT = (unsigned short*)alloc(2 * 128 * 128 * 2);
    __half* Hs       = (__half*)alloc((size_t)N * NODE_F * 2);
    unsigned short* Xhi = (unsigned short*)alloc((size_t)N * NODE_F * 2);
    unsigned short* Xlo = (unsigned short*)alloc((size_t)N * NODE_F * 2);
    (void)ws_size; (void)n_in; (void)out_size;

    const int B = 256;
    const int gemm_grid   = (N + 63) / 64;
    const int edge_grid   = (E + B - 1) / B;
    const int scale_grid  = (N * 16 + B - 1) / B;
    const int gather_grid = (N + 3) / 4;

    wconv_kernel<<<2, B, 0, stream>>>(W1, W2, WhiT, WloT);
    hipMemsetAsync(degE, 0, (size_t)N * 4, stream);

    // [deg_rank || gemm1 (unscaled H)]
    hybridA_kernel<<<edge_grid + gemm_grid, B, 0, stream>>>(
        dst, degE, rank, E, edge_grid, x, WhiT, WloT, Hs, N);

    scan_block_kernel<<<nblk1024, B, 0, stream>>>(degE, row_start, bsum, N);
    scan_tops_kernel<<<1, 1024, 0, stream>>>(bsum, nblk1024);
    scan_finish_kernel<<<(N + B - 1) / B, B, 0, stream>>>(degE, row_start, bsum, dinv, N);

    // [fill || scale H in-place by dinv]
    hybridB_kernel<<<edge_grid + scale_grid, B, 0, stream>>>(
        src, dst, rank, row_start, csr_src, E, edge_grid, Hs, degE, N);

    // layer-1 aggregate -> relu -> split bf16
    gather1_kernel<<<gather_grid, B, 0, stream>>>(Hs, csr_src, row_start, dinv, b1, Xhi, Xlo, N);

    // layer-2 GEMM (pre-split input, scaled epilogue)
    gemm2_kernel<<<gemm_grid, B, 0, stream>>>(Xhi, Xlo, WhiT + 128 * 128, WloT + 128 * 128,
                                              dinv, Hs, N);

    // layer-2 aggregate + FC head
    gather2fc_kernel<<<gather_grid, B, 0, stream>>>(Hs, csr_src, row_start, dinv, b2,
                                                    Wfc, bfc, out, N);
}

// Round 7
// 335.973 us; speedup vs baseline: 16.6383x; 1.0476x over previous
//
#include <hip/hip_runtime.h>
#include <hip/hip_bf16.h>
#include <hip/hip_fp16.h>

// ResidualGNN: 2x GCNConv(128->128, relu) + FC(128->3, tanh), N=100000, E=1.6M, fp32.
// R6: deg_rank thread-interleaved into gemm1 blocks (atomics hide under MFMA);
//     gathers process 2 edges/iter (half-wave each, 8B/lane) + shfl_xor(32) reduce.

#define NODE_F 128

typedef __attribute__((ext_vector_type(8))) short bf16x8;
typedef __attribute__((ext_vector_type(8))) unsigned short u16x8;
typedef __attribute__((ext_vector_type(4))) float f32x4;

__device__ inline unsigned short bf16_rn(float x) {
    unsigned u = __builtin_bit_cast(unsigned, x);
    unsigned r = (u + 0x7fffu + ((u >> 16) & 1u)) >> 16;
    return (unsigned short)r;
}
__device__ inline float bf16_to_f(unsigned short h) {
    unsigned u = (unsigned)h << 16;
    return __builtin_bit_cast(float, u);
}
__device__ inline void acc4_h(float a[4], uint2 v) {
    __half2 h01 = __builtin_bit_cast(__half2, v.x);
    __half2 h23 = __builtin_bit_cast(__half2, v.y);
    float2 f01 = __half22float2(h01), f23 = __half22float2(h23);
    a[0] += f01.x; a[1] += f01.y; a[2] += f23.x; a[3] += f23.y;
}

// ---- W -> bf16 hi/lo, transposed to [n][k]; both weights in one launch --

__global__ __launch_bounds__(256) void wconv_kernel(const float* __restrict__ W1,
                                                    const float* __restrict__ W2,
                                                    unsigned short* __restrict__ WhiT,
                                                    unsigned short* __restrict__ WloT)
{
    const float* W = blockIdx.x ? W2 : W1;
    unsigned short* hiT = WhiT + blockIdx.x * 128 * 128;
    unsigned short* loT = WloT + blockIdx.x * 128 * 128;
    int tid = threadIdx.x;
    for (int i = tid; i < 128 * 128; i += 256) {
        int k = i >> 7, n = i & 127;
        float x = W[i];
        unsigned short hi = bf16_rn(x);
        float lo = x - bf16_to_f(hi);
        hiT[n * 128 + k] = hi;
        loT[n * 128 + k] = bf16_rn(lo);
    }
}

// ---- scan ---------------------------------------------------------------

__global__ __launch_bounds__(256) void scan_block_kernel(
    const int* __restrict__ degE, int* __restrict__ row_start,
    int* __restrict__ bsum, int N)
{
    __shared__ int s[256];
    const int tid = threadIdx.x;
    const int idx = blockIdx.x * 1024 + tid * 4;
    int v0 = (idx + 0 < N) ? degE[idx + 0] : 0;
    int v1 = (idx + 1 < N) ? degE[idx + 1] : 0;
    int v2 = (idx + 2 < N) ? degE[idx + 2] : 0;
    int v3 = (idx + 3 < N) ? degE[idx + 3] : 0;
    int t = v0 + v1 + v2 + v3;
    s[tid] = t;
    __syncthreads();
    #pragma unroll
    for (int off = 1; off < 256; off <<= 1) {
        int x = (tid >= off) ? s[tid - off] : 0;
        __syncthreads();
        s[tid] += x;
        __syncthreads();
    }
    int excl = s[tid] - t;
    if (idx + 0 < N) row_start[idx + 0] = excl;
    if (idx + 1 < N) row_start[idx + 1] = excl + v0;
    if (idx + 2 < N) row_start[idx + 2] = excl + v0 + v1;
    if (idx + 3 < N) row_start[idx + 3] = excl + v0 + v1 + v2;
    if (tid == 255) bsum[blockIdx.x] = s[255];
}

__global__ __launch_bounds__(1024) void scan_tops_kernel(int* __restrict__ bsum, int nb) {
    __shared__ int s[1024];
    const int tid = threadIdx.x;
    int v = (tid < nb) ? bsum[tid] : 0;
    s[tid] = v;
    __syncthreads();
    #pragma unroll
    for (int off = 1; off < 1024; off <<= 1) {
        int x = (tid >= off) ? s[tid - off] : 0;
        __syncthreads();
        s[tid] += x;
        __syncthreads();
    }
    if (tid < nb) bsum[tid] = s[tid] - v;
}

__global__ void scan_finish_kernel(const int* __restrict__ degE, int* __restrict__ row_start,
                                   const int* __restrict__ bsum, float* __restrict__ dinv, int N)
{
    int i = blockIdx.x * blockDim.x + threadIdx.x;
    if (i >= N) return;
    int rs = row_start[i] + bsum[i >> 10];
    row_start[i] = rs;
    dinv[i] = rsqrtf((float)degE[i] + 1.0f);
    if (i == N - 1) row_start[N] = rs + degE[i];
}

// ---- GEMM body ----------------------------------------------------------
// block computes 64 rows x 128 cols with 4 waves; wave w owns cols w*32..+31.

template<bool SPLIT_IN, bool SCALE_OUT>
__device__ __forceinline__ void gemm_body(
    const float* __restrict__ Xf,
    const unsigned short* __restrict__ Xhi_g, const unsigned short* __restrict__ Xlo_g,
    const unsigned short* __restrict__ WhiT, const unsigned short* __restrict__ WloT,
    const float* __restrict__ dinv,
    __half* __restrict__ Hout, int N, int bid,
    unsigned short* xhi, unsigned short* xlo)
{
    const int tid  = threadIdx.x;
    const int lane = tid & 63;
    const int w    = tid >> 6;
    const int rbase = bid * 64;

    bf16x8 bhi[2][4], blo[2][4];
    {
        int n0   = w * 32 + (lane & 15);
        int koct = (lane >> 4) * 8;
        #pragma unroll
        for (int nt = 0; nt < 2; ++nt) {
            #pragma unroll
            for (int kk = 0; kk < 4; ++kk) {
                size_t o = (size_t)(n0 + nt * 16) * 128 + kk * 32 + koct;
                bhi[nt][kk] = *reinterpret_cast<const bf16x8*>(WhiT + o);
                blo[nt][kk] = *reinterpret_cast<const bf16x8*>(WloT + o);
            }
        }
    }

    if (!SPLIT_IN) {
        #pragma unroll
        for (int it = 0; it < 8; ++it) {
            int f   = it * 256 + tid;
            int row = f >> 5;
            int k4  = f & 31;
            float4 v = make_float4(0.f, 0.f, 0.f, 0.f);
            if (rbase + row < N)
                v = *reinterpret_cast<const float4*>(Xf + (size_t)(rbase + row) * NODE_F + k4 * 4);
            float xs[4] = {v.x, v.y, v.z, v.w};
            ushort4 h4, l4;
            unsigned short* hp = &h4.x;
            unsigned short* lp = &l4.x;
            #pragma unroll
            for (int j = 0; j < 4; ++j) {
                unsigned short hi = bf16_rn(xs[j]);
                hp[j] = hi;
                lp[j] = bf16_rn(xs[j] - bf16_to_f(hi));
            }
            int byte = row * 256 + ((k4 * 8) ^ ((row & 7) << 4));
            *reinterpret_cast<ushort4*>(reinterpret_cast<char*>(xhi) + byte) = h4;
            *reinterpret_cast<ushort4*>(reinterpret_cast<char*>(xlo) + byte) = l4;
        }
    } else {
        #pragma unroll
        for (int it = 0; it < 4; ++it) {
            int idx = it * 256 + tid;           // u16x8 units; 1024 per array
            int row = idx >> 4;
            int k8  = idx & 15;
            u16x8 h = {0, 0, 0, 0, 0, 0, 0, 0};
            u16x8 l = {0, 0, 0, 0, 0, 0, 0, 0};
            if (rbase + row < N) {
                size_t g = (size_t)(rbase + row) * NODE_F + k8 * 8;
                h = *reinterpret_cast<const u16x8*>(Xhi_g + g);
                l = *reinterpret_cast<const u16x8*>(Xlo_g + g);
            }
            int byte = row * 256 + ((k8 * 16) ^ ((row & 7) << 4));
            *reinterpret_cast<u16x8*>(reinterpret_cast<char*>(xhi) + byte) = h;
            *reinterpret_cast<u16x8*>(reinterpret_cast<char*>(xlo) + byte) = l;
        }
    }
    __syncthreads();

    f32x4 acc[4][2];
    #pragma unroll
    for (int m = 0; m < 4; ++m)
        #pragma unroll
        for (int nt = 0; nt < 2; ++nt)
            acc[m][nt] = (f32x4){0.f, 0.f, 0.f, 0.f};

    #pragma unroll
    for (int kk = 0; kk < 4; ++kk) {
        #pragma unroll
        for (int m = 0; m < 4; ++m) {
            int row  = m * 16 + (lane & 15);
            int koff = kk * 64 + (lane >> 4) * 16;
            int byte = row * 256 + (koff ^ ((row & 7) << 4));
            bf16x8 ahi = *reinterpret_cast<const bf16x8*>(reinterpret_cast<char*>(xhi) + byte);
            bf16x8 alo = *reinterpret_cast<const bf16x8*>(reinterpret_cast<char*>(xlo) + byte);
            #pragma unroll
            for (int nt = 0; nt < 2; ++nt) {
                acc[m][nt] = __builtin_amdgcn_mfma_f32_16x16x32_bf16(ahi, bhi[nt][kk], acc[m][nt], 0, 0, 0);
                acc[m][nt] = __builtin_amdgcn_mfma_f32_16x16x32_bf16(ahi, blo[nt][kk], acc[m][nt], 0, 0, 0);
                acc[m][nt] = __builtin_amdgcn_mfma_f32_16x16x32_bf16(alo, bhi[nt][kk], acc[m][nt], 0, 0, 0);
            }
        }
    }

    // epilogue: D col = lane&15, row = (lane>>4)*4 + r
    #pragma unroll
    for (int m = 0; m < 4; ++m) {
        int row = rbase + m * 16 + (lane >> 4) * 4;
        int col = w * 32 + (lane & 15);
        #pragma unroll
        for (int nt = 0; nt < 2; ++nt) {
            #pragma unroll
            for (int r = 0; r < 4; ++r) {
                if (row + r < N) {
                    float v = acc[m][nt][r];
                    if (SCALE_OUT) v *= dinv[row + r];
                    Hout[(size_t)(row + r) * NODE_F + col + nt * 16] = __float2half(v);
                }
            }
        }
    }
}

// ---- gemm1 + deg_rank thread-interleaved --------------------------------

__global__ __launch_bounds__(256) void gemm1deg_kernel(
    const int* __restrict__ dst, int* __restrict__ degE, int* __restrict__ rank, int E,
    int total_threads,
    const float* __restrict__ X, const unsigned short* __restrict__ WhiT,
    const unsigned short* __restrict__ WloT, __half* __restrict__ H, int N)
{
    __shared__ unsigned short xhi[64 * 128];
    __shared__ unsigned short xlo[64 * 128];
    // edge work first: atomics retire while the GEMM below runs
    for (int e = blockIdx.x * 256 + threadIdx.x; e < E; e += total_threads)
        rank[e] = atomicAdd(&degE[dst[e]], 1);
    gemm_body<false, false>(X, nullptr, nullptr, WhiT, WloT, nullptr,
                            H, N, blockIdx.x, xhi, xlo);
}

// ---- hybridB: [fill || scale H by dinv (from degE)] ---------------------

__global__ __launch_bounds__(256) void hybridB_kernel(
    const int* __restrict__ src, const int* __restrict__ dst,
    const int* __restrict__ rank, const int* __restrict__ row_start,
    int* __restrict__ csr_src, int E, int fill_blocks,
    __half* __restrict__ H, const int* __restrict__ degE, int N)
{
    if ((int)blockIdx.x < fill_blocks) {
        int e = blockIdx.x * 256 + threadIdx.x;
        if (e < E) csr_src[row_start[dst[e]] + rank[e]] = src[e];
    } else {
        int idx = (blockIdx.x - fill_blocks) * 256 + threadIdx.x;  // 8-half units
        if (idx < N * 16) {
            int row = idx >> 4;
            float ds = rsqrtf((float)degE[row] + 1.0f);
            __half2* p = reinterpret_cast<__half2*>(H) + (size_t)idx * 4;
            #pragma unroll
            for (int j = 0; j < 4; ++j) {
                float2 v = __half22float2(p[j]);
                v.x *= ds; v.y *= ds;
                p[j] = __float22half2_rn(v);
            }
        }
    }
}

// ---- gather core: 2 edges/iter, half-wave per edge, 8B/lane -------------
// returns per-lane a[4] = features (lane&31)*4.. summed over BOTH halves.

__device__ __forceinline__ void gather_core(
    const __half* __restrict__ Hs, const int* __restrict__ csr_src,
    const int* __restrict__ row_start, int node, int li, int h, float a[4])
{
    const char* Hb = reinterpret_cast<const char*>(Hs);
    a[0] = a[1] = a[2] = a[3] = 0.f;
    // self row: half 0 only
    if (h == 0)
        acc4_h(a, *reinterpret_cast<const uint2*>(Hb + ((size_t)node * 256 + li * 8)));

    int i   = row_start[node];
    int end = row_start[node + 1];
    for (; i + 7 < end; i += 8) {
        int s0 = csr_src[i + 0 + h];
        int s1 = csr_src[i + 2 + h];
        int s2 = csr_src[i + 4 + h];
        int s3 = csr_src[i + 6 + h];
        uint2 v0 = *reinterpret_cast<const uint2*>(Hb + ((size_t)s0 * 256 + li * 8));
        uint2 v1 = *reinterpret_cast<const uint2*>(Hb + ((size_t)s1 * 256 + li * 8));
        uint2 v2 = *reinterpret_cast<const uint2*>(Hb + ((size_t)s2 * 256 + li * 8));
        uint2 v3 = *reinterpret_cast<const uint2*>(Hb + ((size_t)s3 * 256 + li * 8));
        acc4_h(a, v0); acc4_h(a, v1); acc4_h(a, v2); acc4_h(a, v3);
    }
    for (; i + 1 < end; i += 2) {
        int s = csr_src[i + h];
        acc4_h(a, *reinterpret_cast<const uint2*>(Hb + ((size_t)s * 256 + li * 8)));
    }
    if (i < end && h == 0) {
        int s = csr_src[i];
        acc4_h(a, *reinterpret_cast<const uint2*>(Hb + ((size_t)s * 256 + li * 8)));
    }
    // cross-half reduce
    #pragma unroll
    for (int j = 0; j < 4; ++j)
        a[j] += __shfl_xor(a[j], 32);
}

// ---- gather1: o = relu(b + dinv[d]*(sum)) -> split bf16 -----------------

__global__ __launch_bounds__(256) void gather1_kernel(
    const __half* __restrict__ Hs, const int* __restrict__ csr_src,
    const int* __restrict__ row_start, const float* __restrict__ dinv,
    const float* __restrict__ b,
    unsigned short* __restrict__ Xhi, unsigned short* __restrict__ Xlo, int N)
{
    int node = (blockIdx.x * blockDim.x + threadIdx.x) >> 6;
    int lane = threadIdx.x & 63;
    int li = lane & 31, h = lane >> 5;
    if (node >= N) return;

    float a[4];
    gather_core(Hs, csr_src, row_start, node, li, h, a);

    if (h == 0) {
        const float dd = dinv[node];
        float4 bb = *reinterpret_cast<const float4*>(b + li * 4);
        float r0 = fmaxf(bb.x + dd * a[0], 0.f);
        float r1 = fmaxf(bb.y + dd * a[1], 0.f);
        float r2 = fmaxf(bb.z + dd * a[2], 0.f);
        float r3 = fmaxf(bb.w + dd * a[3], 0.f);
        ushort4 h4, l4;
        h4.x = bf16_rn(r0); l4.x = bf16_rn(r0 - bf16_to_f(h4.x));
        h4.y = bf16_rn(r1); l4.y = bf16_rn(r1 - bf16_to_f(h4.y));
        h4.z = bf16_rn(r2); l4.z = bf16_rn(r2 - bf16_to_f(h4.z));
        h4.w = bf16_rn(r3); l4.w = bf16_rn(r3 - bf16_to_f(h4.w));
        *reinterpret_cast<ushort4*>(Xhi + (size_t)node * NODE_F + li * 4) = h4;
        *reinterpret_cast<ushort4*>(Xlo + (size_t)node * NODE_F + li * 4) = l4;
    }
}

// ---- gather2 + FC: out = tanh(relu(b + dd*sum) @ Wfc + bfc) -------------

__global__ __launch_bounds__(256) void gather2fc_kernel(
    const __half* __restrict__ Hs, const int* __restrict__ csr_src,
    const int* __restrict__ row_start, const float* __restrict__ dinv,
    const float* __restrict__ b, const float* __restrict__ Wfc,
    const float* __restrict__ bfc, float* __restrict__ out, int N)
{
    int node = (blockIdx.x * blockDim.x + threadIdx.x) >> 6;
    int lane = threadIdx.x & 63;
    int li = lane & 31, h = lane >> 5;
    if (node >= N) return;

    float a[4];
    gather_core(Hs, csr_src, row_start, node, li, h, a);

    const float dd = dinv[node];
    float4 bb = *reinterpret_cast<const float4*>(b + li * 4);
    float bv[4] = {bb.x, bb.y, bb.z, bb.w};
    float p0 = 0.f, p1 = 0.f, p2 = 0.f;
    #pragma unroll
    for (int j = 0; j < 4; ++j) {
        float r = fmaxf(bv[j] + dd * a[j], 0.f);
        const float* wr = Wfc + (size_t)(li * 4 + j) * 3;
        p0 += r * wr[0]; p1 += r * wr[1]; p2 += r * wr[2];
    }
    #pragma unroll
    for (int off = 16; off > 0; off >>= 1) {
        p0 += __shfl_down(p0, off);
        p1 += __shfl_down(p1, off);
        p2 += __shfl_down(p2, off);
    }
    if (lane == 0) {
        out[(size_t)node * 3 + 0] = tanhf(p0 + bfc[0]);
        out[(size_t)node * 3 + 1] = tanhf(p1 + bfc[1]);
        out[(size_t)node * 3 + 2] = tanhf(p2 + bfc[2]);
    }
}

// ---- gemm2 --------------------------------------------------------------

__global__ __launch_bounds__(256) void gemm2_kernel(
    const unsigned short* __restrict__ Xhi_g, const unsigned short* __restrict__ Xlo_g,
    const unsigned short* __restrict__ WhiT, const unsigned short* __restrict__ WloT,
    const float* __restrict__ dinv, __half* __restrict__ Hs, int N)
{
    __shared__ unsigned short xhi[64 * 128];
    __shared__ unsigned short xlo[64 * 128];
    gemm_body<true, true>(nullptr, Xhi_g, Xlo_g, WhiT, WloT, dinv,
                          Hs, N, blockIdx.x, xhi, xlo);
}

extern "C" void kernel_launch(void* const* d_in, const int* in_sizes, int n_in,
                              void* d_out, int out_size, void* d_ws, size_t ws_size,
                              hipStream_t stream)
{
    const float* x    = (const float*)d_in[0];
    const int*   edge = (const int*)d_in[1];
    const float* W1   = (const float*)d_in[2];
    const float* b1   = (const float*)d_in[3];
    const float* W2   = (const float*)d_in[4];
    const float* b2   = (const float*)d_in[5];
    const float* Wfc  = (const float*)d_in[6];
    const float* bfc  = (const float*)d_in[7];
    float* out = (float*)d_out;

    const int N = in_sizes[0] / NODE_F;
    const int E = in_sizes[1] / 2;
    const int* src = edge;
    const int* dst = edge + E;

    char* ws = (char*)d_ws;
    size_t off = 0;
    auto alloc = [&](size_t bytes) {
        void* p = ws + off;
        off += (bytes + 511) & ~511ull;
        return p;
    };
    const int nblk1024 = (N + 1023) / 1024;
    float* dinv      = (float*)alloc((size_t)N * 4);
    int*   degE      = (int*)  alloc((size_t)N * 4);
    int*   rank      = (int*)  alloc((size_t)E * 4);
    int*   row_start = (int*)  alloc((size_t)(N + 1) * 4);
    int*   bsum      = (int*)  alloc((size_t)nblk1024 * 4);
    int*   csr_src   = (int*)  alloc((size_t)E * 4);
    unsigned short* WhiT = (unsigned short*)alloc(2 * 128 * 128 * 2);
    unsigned short* WloT = (unsigned short*)alloc(2 * 128 * 128 * 2);
    __half* Hs       = (__half*)alloc((size_t)N * NODE_F * 2);
    unsigned short* Xhi = (unsigned short*)alloc((size_t)N * NODE_F * 2);
    unsigned short* Xlo = (unsigned short*)alloc((size_t)N * NODE_F * 2);
    (void)ws_size; (void)n_in; (void)out_size;

    const int B = 256;
    const int gemm_grid   = (N + 63) / 64;
    const int edge_grid   = (E + B - 1) / B;
    const int scale_grid  = (N * 16 + B - 1) / B;
    const int gather_grid = (N + 3) / 4;

    wconv_kernel<<<2, B, 0, stream>>>(W1, W2, WhiT, WloT);
    hipMemsetAsync(degE, 0, (size_t)N * 4, stream);

    // gemm1 (unscaled H) with deg_rank interleaved per-thread
    gemm1deg_kernel<<<gemm_grid, B, 0, stream>>>(
        dst, degE, rank, E, gemm_grid * B, x, WhiT, WloT, Hs, N);

    scan_block_kernel<<<nblk1024, B, 0, stream>>>(degE, row_start, bsum, N);
    scan_tops_kernel<<<1, 1024, 0, stream>>>(bsum, nblk1024);
    scan_finish_kernel<<<(N + B - 1) / B, B, 0, stream>>>(degE, row_start, bsum, dinv, N);

    // [fill || scale H in-place by dinv]
    hybridB_kernel<<<edge_grid + scale_grid, B, 0, stream>>>(
        src, dst, rank, row_start, csr_src, E, edge_grid, Hs, degE, N);

    // layer-1 aggregate -> relu -> split bf16
    gather1_kernel<<<gather_grid, B, 0, stream>>>(Hs, csr_src, row_start, dinv, b1, Xhi, Xlo, N);

    // layer-2 GEMM (pre-split input, scaled epilogue)
    gemm2_kernel<<<gemm_grid, B, 0, stream>>>(Xhi, Xlo, WhiT + 128 * 128, WloT + 128 * 128,
                                              dinv, Hs, N);

    // layer-2 aggregate + FC head
    gather2fc_kernel<<<gather_grid, B, 0, stream>>>(Hs, csr_src, row_start, dinv, b2,
                                                    Wfc, bfc, out, N);
}

// Round 8
// 320.775 us; speedup vs baseline: 17.4266x; 1.0474x over previous
//
#include <hip/hip_runtime.h>
#include <hip/hip_bf16.h>
#include <hip/hip_fp16.h>

// ResidualGNN: 2x GCNConv(128->128, relu) + FC(128->3, tanh), N=100000, E=1.6M, fp32.
// R7: deg_rank as 1:4 modulo-interleaved blocks inside gemm1 launch (co-resident,
//     atomics hide under MFMA); gathers quarter-wave (16B/lane, 4 edges/iter,
//     unroll x2 = 8 rows in flight) + shfl_xor(32,16) reduce.

#define NODE_F 128

typedef __attribute__((ext_vector_type(8))) short bf16x8;
typedef __attribute__((ext_vector_type(8))) unsigned short u16x8;
typedef __attribute__((ext_vector_type(4))) float f32x4;

__device__ inline unsigned short bf16_rn(float x) {
    unsigned u = __builtin_bit_cast(unsigned, x);
    unsigned r = (u + 0x7fffu + ((u >> 16) & 1u)) >> 16;
    return (unsigned short)r;
}
__device__ inline float bf16_to_f(unsigned short h) {
    unsigned u = (unsigned)h << 16;
    return __builtin_bit_cast(float, u);
}
__device__ inline void acc8_h(float a[8], uint4 v) {
    unsigned vv[4] = {v.x, v.y, v.z, v.w};
    #pragma unroll
    for (int j = 0; j < 4; ++j) {
        float2 f = __half22float2(__builtin_bit_cast(__half2, vv[j]));
        a[2 * j]     += f.x;
        a[2 * j + 1] += f.y;
    }
}

// ---- W -> bf16 hi/lo, transposed to [n][k]; both weights in one launch --

__global__ __launch_bounds__(256) void wconv_kernel(const float* __restrict__ W1,
                                                    const float* __restrict__ W2,
                                                    unsigned short* __restrict__ WhiT,
                                                    unsigned short* __restrict__ WloT)
{
    const float* W = blockIdx.x ? W2 : W1;
    unsigned short* hiT = WhiT + blockIdx.x * 128 * 128;
    unsigned short* loT = WloT + blockIdx.x * 128 * 128;
    int tid = threadIdx.x;
    for (int i = tid; i < 128 * 128; i += 256) {
        int k = i >> 7, n = i & 127;
        float x = W[i];
        unsigned short hi = bf16_rn(x);
        float lo = x - bf16_to_f(hi);
        hiT[n * 128 + k] = hi;
        loT[n * 128 + k] = bf16_rn(lo);
    }
}

// ---- scan ---------------------------------------------------------------

__global__ __launch_bounds__(256) void scan_block_kernel(
    const int* __restrict__ degE, int* __restrict__ row_start,
    int* __restrict__ bsum, int N)
{
    __shared__ int s[256];
    const int tid = threadIdx.x;
    const int idx = blockIdx.x * 1024 + tid * 4;
    int v0 = (idx + 0 < N) ? degE[idx + 0] : 0;
    int v1 = (idx + 1 < N) ? degE[idx + 1] : 0;
    int v2 = (idx + 2 < N) ? degE[idx + 2] : 0;
    int v3 = (idx + 3 < N) ? degE[idx + 3] : 0;
    int t = v0 + v1 + v2 + v3;
    s[tid] = t;
    __syncthreads();
    #pragma unroll
    for (int off = 1; off < 256; off <<= 1) {
        int x = (tid >= off) ? s[tid - off] : 0;
        __syncthreads();
        s[tid] += x;
        __syncthreads();
    }
    int excl = s[tid] - t;
    if (idx + 0 < N) row_start[idx + 0] = excl;
    if (idx + 1 < N) row_start[idx + 1] = excl + v0;
    if (idx + 2 < N) row_start[idx + 2] = excl + v0 + v1;
    if (idx + 3 < N) row_start[idx + 3] = excl + v0 + v1 + v2;
    if (tid == 255) bsum[blockIdx.x] = s[255];
}

__global__ __launch_bounds__(1024) void scan_tops_kernel(int* __restrict__ bsum, int nb) {
    __shared__ int s[1024];
    const int tid = threadIdx.x;
    int v = (tid < nb) ? bsum[tid] : 0;
    s[tid] = v;
    __syncthreads();
    #pragma unroll
    for (int off = 1; off < 1024; off <<= 1) {
        int x = (tid >= off) ? s[tid - off] : 0;
        __syncthreads();
        s[tid] += x;
        __syncthreads();
    }
    if (tid < nb) bsum[tid] = s[tid] - v;
}

__global__ void scan_finish_kernel(const int* __restrict__ degE, int* __restrict__ row_start,
                                   const int* __restrict__ bsum, float* __restrict__ dinv, int N)
{
    int i = blockIdx.x * blockDim.x + threadIdx.x;
    if (i >= N) return;
    int rs = row_start[i] + bsum[i >> 10];
    row_start[i] = rs;
    dinv[i] = rsqrtf((float)degE[i] + 1.0f);
    if (i == N - 1) row_start[N] = rs + degE[i];
}

// ---- GEMM body ----------------------------------------------------------

template<bool SPLIT_IN, bool SCALE_OUT>
__device__ __forceinline__ void gemm_body(
    const float* __restrict__ Xf,
    const unsigned short* __restrict__ Xhi_g, const unsigned short* __restrict__ Xlo_g,
    const unsigned short* __restrict__ WhiT, const unsigned short* __restrict__ WloT,
    const float* __restrict__ dinv,
    __half* __restrict__ Hout, int N, int bid,
    unsigned short* xhi, unsigned short* xlo)
{
    const int tid  = threadIdx.x;
    const int lane = tid & 63;
    const int w    = tid >> 6;
    const int rbase = bid * 64;

    bf16x8 bhi[2][4], blo[2][4];
    {
        int n0   = w * 32 + (lane & 15);
        int koct = (lane >> 4) * 8;
        #pragma unroll
        for (int nt = 0; nt < 2; ++nt) {
            #pragma unroll
            for (int kk = 0; kk < 4; ++kk) {
                size_t o = (size_t)(n0 + nt * 16) * 128 + kk * 32 + koct;
                bhi[nt][kk] = *reinterpret_cast<const bf16x8*>(WhiT + o);
                blo[nt][kk] = *reinterpret_cast<const bf16x8*>(WloT + o);
            }
        }
    }

    if (!SPLIT_IN) {
        #pragma unroll
        for (int it = 0; it < 8; ++it) {
            int f   = it * 256 + tid;
            int row = f >> 5;
            int k4  = f & 31;
            float4 v = make_float4(0.f, 0.f, 0.f, 0.f);
            if (rbase + row < N)
                v = *reinterpret_cast<const float4*>(Xf + (size_t)(rbase + row) * NODE_F + k4 * 4);
            float xs[4] = {v.x, v.y, v.z, v.w};
            ushort4 h4, l4;
            unsigned short* hp = &h4.x;
            unsigned short* lp = &l4.x;
            #pragma unroll
            for (int j = 0; j < 4; ++j) {
                unsigned short hi = bf16_rn(xs[j]);
                hp[j] = hi;
                lp[j] = bf16_rn(xs[j] - bf16_to_f(hi));
            }
            int byte = row * 256 + ((k4 * 8) ^ ((row & 7) << 4));
            *reinterpret_cast<ushort4*>(reinterpret_cast<char*>(xhi) + byte) = h4;
            *reinterpret_cast<ushort4*>(reinterpret_cast<char*>(xlo) + byte) = l4;
        }
    } else {
        #pragma unroll
        for (int it = 0; it < 4; ++it) {
            int idx = it * 256 + tid;
            int row = idx >> 4;
            int k8  = idx & 15;
            u16x8 h = {0, 0, 0, 0, 0, 0, 0, 0};
            u16x8 l = {0, 0, 0, 0, 0, 0, 0, 0};
            if (rbase + row < N) {
                size_t g = (size_t)(rbase + row) * NODE_F + k8 * 8;
                h = *reinterpret_cast<const u16x8*>(Xhi_g + g);
                l = *reinterpret_cast<const u16x8*>(Xlo_g + g);
            }
            int byte = row * 256 + ((k8 * 16) ^ ((row & 7) << 4));
            *reinterpret_cast<u16x8*>(reinterpret_cast<char*>(xhi) + byte) = h;
            *reinterpret_cast<u16x8*>(reinterpret_cast<char*>(xlo) + byte) = l;
        }
    }
    __syncthreads();

    f32x4 acc[4][2];
    #pragma unroll
    for (int m = 0; m < 4; ++m)
        #pragma unroll
        for (int nt = 0; nt < 2; ++nt)
            acc[m][nt] = (f32x4){0.f, 0.f, 0.f, 0.f};

    #pragma unroll
    for (int kk = 0; kk < 4; ++kk) {
        #pragma unroll
        for (int m = 0; m < 4; ++m) {
            int row  = m * 16 + (lane & 15);
            int koff = kk * 64 + (lane >> 4) * 16;
            int byte = row * 256 + (koff ^ ((row & 7) << 4));
            bf16x8 ahi = *reinterpret_cast<const bf16x8*>(reinterpret_cast<char*>(xhi) + byte);
            bf16x8 alo = *reinterpret_cast<const bf16x8*>(reinterpret_cast<char*>(xlo) + byte);
            #pragma unroll
            for (int nt = 0; nt < 2; ++nt) {
                acc[m][nt] = __builtin_amdgcn_mfma_f32_16x16x32_bf16(ahi, bhi[nt][kk], acc[m][nt], 0, 0, 0);
                acc[m][nt] = __builtin_amdgcn_mfma_f32_16x16x32_bf16(ahi, blo[nt][kk], acc[m][nt], 0, 0, 0);
                acc[m][nt] = __builtin_amdgcn_mfma_f32_16x16x32_bf16(alo, bhi[nt][kk], acc[m][nt], 0, 0, 0);
            }
        }
    }

    #pragma unroll
    for (int m = 0; m < 4; ++m) {
        int row = rbase + m * 16 + (lane >> 4) * 4;
        int col = w * 32 + (lane & 15);
        #pragma unroll
        for (int nt = 0; nt < 2; ++nt) {
            #pragma unroll
            for (int r = 0; r < 4; ++r) {
                if (row + r < N) {
                    float v = acc[m][nt][r];
                    if (SCALE_OUT) v *= dinv[row + r];
                    Hout[(size_t)(row + r) * NODE_F + col + nt * 16] = __float2half(v);
                }
            }
        }
    }
}

// ---- gemm1 + deg_rank as 1:4 modulo-interleaved block roles -------------

__global__ __launch_bounds__(256) void gemm1deg_kernel(
    const int* __restrict__ dst, int* __restrict__ degE, int* __restrict__ rank, int E,
    int edge_blocks, int gemm_blocks,
    const float* __restrict__ X, const unsigned short* __restrict__ WhiT,
    const unsigned short* __restrict__ WloT, __half* __restrict__ H, int N)
{
    __shared__ unsigned short xhi[64 * 128];
    __shared__ unsigned short xlo[64 * 128];
    int q = blockIdx.x / 5, r = blockIdx.x % 5;
    if (r == 4) {
        // edge role: grid-stride over all edges
        int stride = edge_blocks * 256;
        for (int e = q * 256 + threadIdx.x; e < E; e += stride)
            rank[e] = atomicAdd(&degE[dst[e]], 1);
    } else {
        int gid = q * 4 + r;
        if (gid < gemm_blocks)
            gemm_body<false, false>(X, nullptr, nullptr, WhiT, WloT, nullptr,
                                    H, N, gid, xhi, xlo);
    }
}

// ---- hybridB: [fill || scale H by dinv (from degE)] ---------------------

__global__ __launch_bounds__(256) void hybridB_kernel(
    const int* __restrict__ src, const int* __restrict__ dst,
    const int* __restrict__ rank, const int* __restrict__ row_start,
    int* __restrict__ csr_src, int E, int fill_blocks,
    __half* __restrict__ H, const int* __restrict__ degE, int N)
{
    if ((int)blockIdx.x < fill_blocks) {
        int e = blockIdx.x * 256 + threadIdx.x;
        if (e < E) csr_src[row_start[dst[e]] + rank[e]] = src[e];
    } else {
        int idx = (blockIdx.x - fill_blocks) * 256 + threadIdx.x;  // 8-half units
        if (idx < N * 16) {
            int row = idx >> 4;
            float ds = rsqrtf((float)degE[row] + 1.0f);
            __half2* p = reinterpret_cast<__half2*>(H) + (size_t)idx * 4;
            #pragma unroll
            for (int j = 0; j < 4; ++j) {
                float2 v = __half22float2(p[j]);
                v.x *= ds; v.y *= ds;
                p[j] = __float22half2_rn(v);
            }
        }
    }
}

// ---- gather core: quarter-wave per edge, 16B/lane, 8 rows in flight -----
// lane = qi*16 + ql; after reduce, ALL lanes hold a[8] = features ql*8..+7.

__device__ __forceinline__ void gather_core(
    const __half* __restrict__ Hs, const int* __restrict__ csr_src,
    const int* __restrict__ row_start, int node, int ql, int qi, float a[8])
{
    const char* Hb = reinterpret_cast<const char*>(Hs);
    #pragma unroll
    for (int j = 0; j < 8; ++j) a[j] = 0.f;
    if (qi == 0)
        acc8_h(a, *reinterpret_cast<const uint4*>(Hb + ((size_t)node * 256 + ql * 16)));

    int i   = row_start[node];
    int end = row_start[node + 1];
    for (; i + 7 < end; i += 8) {
        int s0 = csr_src[i + qi];
        int s1 = csr_src[i + 4 + qi];
        uint4 v0 = *reinterpret_cast<const uint4*>(Hb + ((size_t)s0 * 256 + ql * 16));
        uint4 v1 = *reinterpret_cast<const uint4*>(Hb + ((size_t)s1 * 256 + ql * 16));
        acc8_h(a, v0);
        acc8_h(a, v1);
    }
    for (; i < end; i += 4) {
        if (i + qi < end) {
            int s = csr_src[i + qi];
            acc8_h(a, *reinterpret_cast<const uint4*>(Hb + ((size_t)s * 256 + ql * 16)));
        }
    }
    // reduce across the 4 quarters
    #pragma unroll
    for (int j = 0; j < 8; ++j) {
        a[j] += __shfl_xor(a[j], 32);
        a[j] += __shfl_xor(a[j], 16);
    }
}

// ---- gather1: o = relu(b + dinv[d]*(sum)) -> split bf16 -----------------

__global__ __launch_bounds__(256) void gather1_kernel(
    const __half* __restrict__ Hs, const int* __restrict__ csr_src,
    const int* __restrict__ row_start, const float* __restrict__ dinv,
    const float* __restrict__ b,
    unsigned short* __restrict__ Xhi, unsigned short* __restrict__ Xlo, int N)
{
    int node = (blockIdx.x * blockDim.x + threadIdx.x) >> 6;
    int lane = threadIdx.x & 63;
    int ql = lane & 15, qi = lane >> 4;
    if (node >= N) return;

    float a[8];
    gather_core(Hs, csr_src, row_start, node, ql, qi, a);

    if (qi == 0) {
        const float dd = dinv[node];
        u16x8 h8, l8;
        #pragma unroll
        for (int j = 0; j < 8; ++j) {
            float r = fmaxf(b[ql * 8 + j] + dd * a[j], 0.f);
            unsigned short hi = bf16_rn(r);
            h8[j] = hi;
            l8[j] = bf16_rn(r - bf16_to_f(hi));
        }
        *reinterpret_cast<u16x8*>(Xhi + (size_t)node * NODE_F + ql * 8) = h8;
        *reinterpret_cast<u16x8*>(Xlo + (size_t)node * NODE_F + ql * 8) = l8;
    }
}

// ---- gather2 + FC: out = tanh(relu(b + dd*sum) @ Wfc + bfc) -------------

__global__ __launch_bounds__(256) void gather2fc_kernel(
    const __half* __restrict__ Hs, const int* __restrict__ csr_src,
    const int* __restrict__ row_start, const float* __restrict__ dinv,
    const float* __restrict__ b, const float* __restrict__ Wfc,
    const float* __restrict__ bfc, float* __restrict__ out, int N)
{
    int node = (blockIdx.x * blockDim.x + threadIdx.x) >> 6;
    int lane = threadIdx.x & 63;
    int ql = lane & 15, qi = lane >> 4;
    if (node >= N) return;

    float a[8];
    gather_core(Hs, csr_src, row_start, node, ql, qi, a);

    const float dd = dinv[node];
    float p0 = 0.f, p1 = 0.f, p2 = 0.f;
    #pragma unroll
    for (int j = 0; j < 8; ++j) {
        float r = fmaxf(b[ql * 8 + j] + dd * a[j], 0.f);
        const float* wr = Wfc + (size_t)(ql * 8 + j) * 3;
        p0 += r * wr[0]; p1 += r * wr[1]; p2 += r * wr[2];
    }
    // reduce across 16 lanes (all quarters computed identical partials per ql)
    #pragma unroll
    for (int off = 8; off > 0; off >>= 1) {
        p0 += __shfl_down(p0, off);
        p1 += __shfl_down(p1, off);
        p2 += __shfl_down(p2, off);
    }
    if (lane == 0) {
        out[(size_t)node * 3 + 0] = tanhf(p0 + bfc[0]);
        out[(size_t)node * 3 + 1] = tanhf(p1 + bfc[1]);
        out[(size_t)node * 3 + 2] = tanhf(p2 + bfc[2]);
    }
}

// ---- gemm2 --------------------------------------------------------------

__global__ __launch_bounds__(256) void gemm2_kernel(
    const unsigned short* __restrict__ Xhi_g, const unsigned short* __restrict__ Xlo_g,
    const unsigned short* __restrict__ WhiT, const unsigned short* __restrict__ WloT,
    const float* __restrict__ dinv, __half* __restrict__ Hs, int N)
{
    __shared__ unsigned short xhi[64 * 128];
    __shared__ unsigned short xlo[64 * 128];
    gemm_body<true, true>(nullptr, Xhi_g, Xlo_g, WhiT, WloT, dinv,
                          Hs, N, blockIdx.x, xhi, xlo);
}

extern "C" void kernel_launch(void* const* d_in, const int* in_sizes, int n_in,
                              void* d_out, int out_size, void* d_ws, size_t ws_size,
                              hipStream_t stream)
{
    const float* x    = (const float*)d_in[0];
    const int*   edge = (const int*)d_in[1];
    const float* W1   = (const float*)d_in[2];
    const float* b1   = (const float*)d_in[3];
    const float* W2   = (const float*)d_in[4];
    const float* b2   = (const float*)d_in[5];
    const float* Wfc  = (const float*)d_in[6];
    const float* bfc  = (const float*)d_in[7];
    float* out = (float*)d_out;

    const int N = in_sizes[0] / NODE_F;
    const int E = in_sizes[1] / 2;
    const int* src = edge;
    const int* dst = edge + E;

    char* ws = (char*)d_ws;
    size_t off = 0;
    auto alloc = [&](size_t bytes) {
        void* p = ws + off;
        off += (bytes + 511) & ~511ull;
        return p;
    };
    const int nblk1024 = (N + 1023) / 1024;
    float* dinv      = (float*)alloc((size_t)N * 4);
    int*   degE      = (int*)  alloc((size_t)N * 4);
    int*   rank      = (int*)  alloc((size_t)E * 4);
    int*   row_start = (int*)  alloc((size_t)(N + 1) * 4);
    int*   bsum      = (int*)  alloc((size_t)nblk1024 * 4);
    int*   csr_src   = (int*)  alloc((size_t)E * 4);
    unsigned short* WhiT = (unsigned short*)alloc(2 * 128 * 128 * 2);
    unsigned short* WloT = (unsigned short*)alloc(2 * 128 * 128 * 2);
    __half* Hs       = (__half*)alloc((size_t)N * NODE_F * 2);
    unsigned short* Xhi = (unsigned short*)alloc((size_t)N * NODE_F * 2);
    unsigned short* Xlo = (unsigned short*)alloc((size_t)N * NODE_F * 2);
    (void)ws_size; (void)n_in; (void)out_size;

    const int B = 256;
    const int gemm_grid   = (N + 63) / 64;                 // 1563
    const int edge_grid   = (E + B - 1) / B;
    const int scale_grid  = (N * 16 + B - 1) / B;
    const int gather_grid = (N + 3) / 4;

    // 1:4 interleave: total blocks T, every 5th is an edge block
    const int edge_blocks  = (gemm_grid + 3) / 4;          // ~391
    const int total_blocks = gemm_grid + edge_blocks + 4;  // margin for modulo mapping

    wconv_kernel<<<2, B, 0, stream>>>(W1, W2, WhiT, WloT);
    hipMemsetAsync(degE, 0, (size_t)N * 4, stream);

    // gemm1 (unscaled H) with deg_rank as interleaved block roles
    gemm1deg_kernel<<<total_blocks, B, 0, stream>>>(
        dst, degE, rank, E, edge_blocks, gemm_grid, x, WhiT, WloT, Hs, N);

    scan_block_kernel<<<nblk1024, B, 0, stream>>>(degE, row_start, bsum, N);
    scan_tops_kernel<<<1, 1024, 0, stream>>>(bsum, nblk1024);
    scan_finish_kernel<<<(N + B - 1) / B, B, 0, stream>>>(degE, row_start, bsum, dinv, N);

    // [fill || scale H in-place by dinv]
    hybridB_kernel<<<edge_grid + scale_grid, B, 0, stream>>>(
        src, dst, rank, row_start, csr_src, E, edge_grid, Hs, degE, N);

    // layer-1 aggregate -> relu -> split bf16
    gather1_kernel<<<gather_grid, B, 0, stream>>>(Hs, csr_src, row_start, dinv, b1, Xhi, Xlo, N);

    // layer-2 GEMM (pre-split input, scaled epilogue)
    gemm2_kernel<<<gemm_grid, B, 0, stream>>>(Xhi, Xlo, WhiT + 128 * 128, WloT + 128 * 128,
                                              dinv, Hs, N);

    // layer-2 aggregate + FC head
    gather2fc_kernel<<<gather_grid, B, 0, stream>>>(Hs, csr_src, row_start, dinv, b2,
                                                    Wfc, bfc, out, N);
}